// Round 8
// baseline (257.165 us; speedup 1.0000x reference)
//
#include <hip/hip_runtime.h>
#include <hip/hip_bf16.h>
#include <math.h>

#define L_TOK 4096
#define D_DIM 576
#define NHEADS 8
#define DHEAD 72
#define DPAD 96
#define HSZ ((size_t)NHEADS * L_TOK * DPAD)   // elems per Q/K/V tensor
#define LOG2E 1.4426950408889634f

typedef __attribute__((ext_vector_type(8))) short short8;
typedef __attribute__((ext_vector_type(4))) short short4v;
typedef __attribute__((ext_vector_type(4))) float float4v;

union F4S8 {
  float4 f4;
  short8 s8;
  __hip_bfloat16 h[8];
};

// ---------------------------------------------------------------------------
// K1: unfold 3x3 s2 p1 -> xb bf16 [4096][576], LDS-tiled (coalesced both ways)
// Block = (ho, cgroup of 8 channels). Loads fea rows 2ho-1..2ho+1 for 8 c
// into Lf[24][130] (w+1 offset, zero side cols); stores 64 wo x 9 float4.
// ---------------------------------------------------------------------------
__global__ __launch_bounds__(256) void unfold_kernel(const float* __restrict__ fea,
                                                     __hip_bfloat16* __restrict__ x) {
  __shared__ float Lf[24 * 130];
  const int ho = blockIdx.x;      // 0..63
  const int c0 = blockIdx.y * 8;  // channel group
  const int t = threadIdx.x;

  for (int e = t; e < 8 * 3 * 128; e += 256) {
    int c = e >> 8;               // /(3*128) ... 3*128=384; use div
    c = e / 384;
    int rr = (e / 128) % 3;
    int w = e & 127;
    int h = 2 * ho + rr - 1;
    float v = 0.f;
    if ((unsigned)h < 128u) v = fea[(size_t)(c0 + c) * 16384 + h * 128 + w];
    Lf[(c * 3 + rr) * 130 + w + 1] = v;
  }
  if (t < 24) { Lf[t * 130] = 0.f; Lf[t * 130 + 129] = 0.f; }
  __syncthreads();

  for (int e = t; e < 576; e += 256) {
    int wo = e / 9, ch = e - wo * 9;
    F4S8 u;
#pragma unroll
    for (int j = 0; j < 8; j++) {
      int dd = ch * 8 + j;
      int c = dd / 9, k = dd - c * 9;
      int ki = k / 3, kj = k - ki * 3;
      u.h[j] = __float2bfloat16(Lf[(c * 3 + ki) * 130 + 2 * wo + kj]);
    }
    *(float4*)(x + (size_t)(ho * 64 + wo) * D_DIM + c0 * 9 + ch * 8) = u.f4;
  }
}

// ---------------------------------------------------------------------------
// fused weight prep: w_qkv^T, w_out^T (fp32->bf16 transpose), conv_w cvt
// ---------------------------------------------------------------------------
__device__ inline void tc_body(const float* __restrict__ src,
                               __hip_bfloat16* __restrict__ dst, int R, int C,
                               int bi, int bj, int t, __hip_bfloat16* Ts) {
  const int col = t & 63, row4 = t >> 6;
#pragma unroll
  for (int u = 0; u < 16; u++) {
    int r = u * 4 + row4;
    Ts[r * 68 + col] = __float2bfloat16(src[(size_t)(bj * 64 + r) * C + bi * 64 + col]);
  }
  __syncthreads();
#pragma unroll
  for (int u = 0; u < 16; u++) {
    int c = u * 4 + row4;
    dst[(size_t)(bi * 64 + c) * R + bj * 64 + col] = Ts[col * 68 + c];
  }
}

__global__ __launch_bounds__(256) void prep_weights(const float* __restrict__ w_qkv,
                                                    const float* __restrict__ w_out,
                                                    const float* __restrict__ conv_w,
                                                    __hip_bfloat16* __restrict__ WqkvT,
                                                    __hip_bfloat16* __restrict__ WoT,
                                                    __hip_bfloat16* __restrict__ CwB) {
  __shared__ __hip_bfloat16 Ts[64 * 68];
  int b = blockIdx.x;
  int t = threadIdx.x;
  if (b < 243) {                    // w_qkv: [576][1728] -> [1728][576]
    tc_body(w_qkv, WqkvT, D_DIM, 1728, b % 27, b / 27, t, Ts);
  } else if (b < 324) {             // w_out: [576][576] -> [576][576]^T
    b -= 243;
    tc_body(w_out, WoT, D_DIM, D_DIM, b % 9, b / 9, t, Ts);
  } else {                          // conv_w: elementwise cvt, 128*576 elems
    int i = (b - 324) * 256 + t;
    CwB[i] = __float2bfloat16(conv_w[i]);
  }
}

// ---------------------------------------------------------------------------
// V transpose (proven R2 pattern): Vb [h][4096][96] -> VbT [h][96][4096]
// ---------------------------------------------------------------------------
__global__ __launch_bounds__(256) void transpose_v(const __hip_bfloat16* __restrict__ Vb,
                                                   __hip_bfloat16* __restrict__ VbT) {
  __shared__ __hip_bfloat16 Ts[96 * 88];
  const int h = blockIdx.y;
  const int m0 = blockIdx.x * 64;
  const int t = threadIdx.x;
  const __hip_bfloat16* src = Vb + ((size_t)h * L_TOK + m0) * DPAD;
  const int m = t & 63;
#pragma unroll
  for (int u = 0; u < 3; u++) {
    int ch = u * 4 + (t >> 6);      // 0..11
    F4S8 xu;
    xu.f4 = *(const float4*)(src + (size_t)m * DPAD + ch * 8);
#pragma unroll
    for (int j = 0; j < 8; j++) Ts[(ch * 8 + j) * 88 + m] = xu.h[j];
  }
  __syncthreads();
  __hip_bfloat16* dstb = VbT + (size_t)h * DPAD * L_TOK + m0;
  const int ch2 = t & 7;
#pragma unroll
  for (int u = 0; u < 3; u++) {
    int d = u * 32 + (t >> 3);      // 0..95
    *(float4*)(dstb + (size_t)d * L_TOK + ch2 * 8) = *(const float4*)(&Ts[d * 88 + ch2 * 8]);
  }
}

// ---------------------------------------------------------------------------
// bf16 MFMA GEMM: C[M][N] = A[M][576] @ Bt[N][576]^T (+epilogue)
// EPI: 0 = QKV scatter(+bias) -> [part][h][L][96] (all coalesced)
//      1 = oproj(+bias+residual->bf16)
// ---------------------------------------------------------------------------
template <int EPI>
__global__ __launch_bounds__(256) void gemm_mfma(const __hip_bfloat16* __restrict__ A,
                                                 const __hip_bfloat16* __restrict__ Bt,
                                                 const float* __restrict__ bias,
                                                 const __hip_bfloat16* __restrict__ resid,
                                                 __hip_bfloat16* __restrict__ outB) {
  constexpr int K = D_DIM;
  __shared__ __align__(16) __hip_bfloat16 As[128 * 72];
  __shared__ __align__(16) __hip_bfloat16 Bs[64 * 72];
  const int t = threadIdx.x;
  const int wave = t >> 6, lane = t & 63, quad = lane >> 4, l16 = lane & 15;
  const int wm = (wave & 2) * 32;   // 0 or 64
  const int wn = (wave & 1) * 32;   // 0 or 32
  const int m0 = blockIdx.x * 128, n0 = blockIdx.y * 64;

  float4v acc[4][2];
#pragma unroll
  for (int i = 0; i < 4; i++)
#pragma unroll
    for (int j = 0; j < 2; j++) acc[i][j] = (float4v){0.f, 0.f, 0.f, 0.f};

  const int arow = t >> 3, ach = t & 7;
  for (int k0 = 0; k0 < K; k0 += 64) {
    __syncthreads();
#pragma unroll
    for (int u = 0; u < 4; u++) {
      int row = u * 32 + arow;
      *(float4*)(&As[row * 72 + ach * 8]) =
          *(const float4*)(A + (size_t)(m0 + row) * K + k0 + ach * 8);
    }
#pragma unroll
    for (int u = 0; u < 2; u++) {
      int row = u * 32 + arow;
      *(float4*)(&Bs[row * 72 + ach * 8]) =
          *(const float4*)(Bt + (size_t)(n0 + row) * K + k0 + ach * 8);
    }
    __syncthreads();
    short8 af[4][2], bfr[2][2];
#pragma unroll
    for (int i = 0; i < 4; i++)
#pragma unroll
      for (int s = 0; s < 2; s++)
        af[i][s] = *(const short8*)(&As[(wm + i * 16 + l16) * 72 + s * 32 + quad * 8]);
#pragma unroll
    for (int j = 0; j < 2; j++)
#pragma unroll
      for (int s = 0; s < 2; s++)
        bfr[j][s] = *(const short8*)(&Bs[(wn + j * 16 + l16) * 72 + s * 32 + quad * 8]);
#pragma unroll
    for (int i = 0; i < 4; i++)
#pragma unroll
      for (int j = 0; j < 2; j++) {
        acc[i][j] = __builtin_amdgcn_mfma_f32_16x16x32_bf16(af[i][0], bfr[j][0], acc[i][j], 0, 0, 0);
        acc[i][j] = __builtin_amdgcn_mfma_f32_16x16x32_bf16(af[i][1], bfr[j][1], acc[i][j], 0, 0, 0);
      }
  }

  // epilogue; C/D layout: col = l16 (n), row = quad*4 + r (m)
  if (EPI == 0) {
    const int part = n0 / D_DIM;          // block lies in exactly one of Q/K/V
    __hip_bfloat16* dst = outB + (size_t)part * HSZ;
#pragma unroll
    for (int j = 0; j < 2; j++) {
      int ng = n0 + wn + j * 16 + l16;
      float bv = bias[ng];
      int rem = ng - part * D_DIM;
      int h = rem / DHEAD;
      int d = rem - h * DHEAD;
#pragma unroll
      for (int i = 0; i < 4; i++) {
        int mb = m0 + wm + i * 16 + quad * 4;
#pragma unroll
        for (int r = 0; r < 4; r++)
          dst[((size_t)h * L_TOK + mb + r) * DPAD + d] = __float2bfloat16(acc[i][j][r] + bv);
      }
    }
  } else {
#pragma unroll
    for (int j = 0; j < 2; j++) {
      int ng = n0 + wn + j * 16 + l16;
      float bv = bias[ng];
#pragma unroll
      for (int i = 0; i < 4; i++) {
        int mb = m0 + wm + i * 16 + quad * 4;
#pragma unroll
        for (int r = 0; r < 4; r++) {
          size_t idx = (size_t)(mb + r) * D_DIM + ng;
          float v = acc[i][j][r] + bv + __bfloat162float(resid[idx]);
          outB[idx] = __float2bfloat16(v);
        }
      }
    }
  }
}

// ---------------------------------------------------------------------------
// final conv GEMM + SiLU: BM=64, BN=32, grid (64,4)=256 WGs.
// ---------------------------------------------------------------------------
__global__ __launch_bounds__(256) void final_small(const __hip_bfloat16* __restrict__ A,
                                                   const __hip_bfloat16* __restrict__ Bt,
                                                   float* __restrict__ out) {
  __shared__ __align__(16) __hip_bfloat16 As[64 * 72];
  __shared__ __align__(16) __hip_bfloat16 Bs[32 * 72];
  const int t = threadIdx.x;
  const int wave = t >> 6, lane = t & 63, quad = lane >> 4, l16 = lane & 15;
  const int wm = (wave & 2) * 16;   // 0 or 32
  const int wn = (wave & 1) * 16;   // 0 or 16
  const int m0 = blockIdx.x * 64, n0 = blockIdx.y * 32;

  float4v acc[2];
  acc[0] = (float4v){0.f, 0.f, 0.f, 0.f};
  acc[1] = (float4v){0.f, 0.f, 0.f, 0.f};

  const int arow = t >> 3, ach = t & 7;
  for (int k0 = 0; k0 < D_DIM; k0 += 64) {
    __syncthreads();
#pragma unroll
    for (int u = 0; u < 2; u++) {
      int row = u * 32 + arow;
      *(float4*)(&As[row * 72 + ach * 8]) =
          *(const float4*)(A + (size_t)(m0 + row) * D_DIM + k0 + ach * 8);
    }
    if (arow < 32)
      *(float4*)(&Bs[arow * 72 + ach * 8]) =
          *(const float4*)(Bt + (size_t)(n0 + arow) * D_DIM + k0 + ach * 8);
    __syncthreads();
    short8 af[2][2], bfr[2];
#pragma unroll
    for (int i = 0; i < 2; i++)
#pragma unroll
      for (int s = 0; s < 2; s++)
        af[i][s] = *(const short8*)(&As[(wm + i * 16 + l16) * 72 + s * 32 + quad * 8]);
#pragma unroll
    for (int s = 0; s < 2; s++)
      bfr[s] = *(const short8*)(&Bs[(wn + l16) * 72 + s * 32 + quad * 8]);
#pragma unroll
    for (int i = 0; i < 2; i++) {
      acc[i] = __builtin_amdgcn_mfma_f32_16x16x32_bf16(af[i][0], bfr[0], acc[i], 0, 0, 0);
      acc[i] = __builtin_amdgcn_mfma_f32_16x16x32_bf16(af[i][1], bfr[1], acc[i], 0, 0, 0);
    }
  }
  const int oc = n0 + wn + l16;
#pragma unroll
  for (int i = 0; i < 2; i++) {
    int mb = m0 + wm + i * 16 + quad * 4;
#pragma unroll
    for (int r = 0; r < 4; r++) {
      float v = acc[i][r];
      float sg = 1.f / (1.f + __expf(-v));
      out[(size_t)oc * L_TOK + mb + r] = v * sg;
    }
  }
}

// ---------------------------------------------------------------------------
// bf16 MFMA flash attention, S^T formulation, LDS-staged K/V, 64 q per wave.
// WG = 4 waves x 64 q; grid = 16 qblk x KSP x 8 heads. Softmax in log2 domain.
// Ps halved (two-pass PV, same-wave ordering) -> LDS 43.3 KB -> 3 WG/CU at
// KSP=6 (grid 768). Opart 72 cols. Tiles split base/base+1 over KSP.
// ---------------------------------------------------------------------------
#define KS_STRIDE 104
#define VT_STRIDE 72
#define PS_STRIDE 72

template <int KSP>
__global__ __launch_bounds__(256, 2) void attn_mfma(const __hip_bfloat16* __restrict__ Qb,
                                                    const __hip_bfloat16* __restrict__ Kb,
                                                    const __hip_bfloat16* __restrict__ VbT,
                                                    __hip_bfloat16* __restrict__ Opart,
                                                    float* __restrict__ Ml) {
  __shared__ __align__(16) __hip_bfloat16 Ks[64 * KS_STRIDE];      // 13312 B
  __shared__ __align__(16) __hip_bfloat16 Vt[80 * VT_STRIDE];      // 11520 B
  __shared__ __align__(16) __hip_bfloat16 Ps[4 * 32 * PS_STRIDE];  // 18432 B

  const int bid = blockIdx.x;
  const int h = bid & 7;                  // head -> XCD affinity
  const int rest = bid >> 3;
  const int ksp = rest % KSP;
  const int qblk = rest / KSP;            // 0..15
  const int t = threadIdx.x;
  const int wave = t >> 6;
  const int lane = t & 63;
  const int quad = lane >> 4;
  const int l16 = lane & 15;

  constexpr int tbase = 64 / KSP, trem = 64 % KSP;
  const int ntiles = (ksp < trem) ? tbase + 1 : tbase;
  const int tstart = (ksp < trem) ? ksp * (tbase + 1)
                                  : trem * (tbase + 1) + (ksp - trem) * tbase;

  const __hip_bfloat16* Qh = Qb + (size_t)h * L_TOK * DPAD;
  const __hip_bfloat16* Kh = Kb + (size_t)h * L_TOK * DPAD;
  const __hip_bfloat16* VhT = VbT + (size_t)h * DPAD * L_TOK;

  // Q as MFMA B operand: lane holds Q[q=l16][d=s*32+quad*8+j]; d>=72 pad -> 0
  const int qbase = qblk * 256 + wave * 64;
  short8 qf[4][3];
#pragma unroll
  for (int mi = 0; mi < 4; mi++) {
#pragma unroll
    for (int s = 0; s < 3; s++) {
      if (s == 2 && quad >= 1) {
        qf[mi][s] = (short8){0, 0, 0, 0, 0, 0, 0, 0};
      } else {
        qf[mi][s] = *(const short8*)(Qh + (size_t)(qbase + mi * 16 + l16) * DPAD + s * 32 + quad * 8);
      }
    }
  }

  // one-time zero of Ks pad cols 72..95 (stale-LDS NaN guard)
  const float4 zero4 = {0.f, 0.f, 0.f, 0.f};
  if (t < 192) {
    int row = t / 3, ch = 9 + t % 3;
    *(float4*)(&Ks[row * KS_STRIDE + ch * 8]) = zero4;
  }

  float4v Of[4][5];
#pragma unroll
  for (int mi = 0; mi < 4; mi++)
#pragma unroll
    for (int nt = 0; nt < 5; nt++) Of[mi][nt] = (float4v){0.f, 0.f, 0.f, 0.f};
  float mrow[4] = {-INFINITY, -INFINITY, -INFINITY, -INFINITY};  // log2 domain
  float lrow[4] = {0.f, 0.f, 0.f, 0.f};
  const float scale2 = 0.11785113019775792f * LOG2E;  // 72^-0.5 * log2(e)

  __hip_bfloat16* myPs = Ps + wave * 32 * PS_STRIDE;

  for (int kt = 0; kt < ntiles; kt++) {
    const int kbase = (tstart + kt) * 64;
    __syncthreads();  // prior tile's K/V reads complete

    // stage K tile [64 keys][d<72] : 576 chunks
    for (int e = t; e < 576; e += 256) {
      int row = e / 9, ch = e - row * 9;
      *(float4*)(&Ks[row * KS_STRIDE + ch * 8]) =
          *(const float4*)(Kh + (size_t)(kbase + row) * DPAD + ch * 8);
    }
    // stage V^T tile [80 d][64 keys] (d>=72 garbage but finite)
    for (int e = t; e < 640; e += 256) {
      int d = e >> 3, ch = e & 7;
      *(float4*)(&Vt[d * VT_STRIDE + ch * 8]) =
          *(const float4*)(VhT + (size_t)d * L_TOK + kbase + ch * 8);
    }
    __syncthreads();

    // S^T = K Q^T (log2-scaled): A = K-frag shared across 4 q-frags
    float4v S[4][4];
#pragma unroll
    for (int ks = 0; ks < 4; ks++) {
      float4v a0 = (float4v){0.f, 0.f, 0.f, 0.f};
      float4v a1 = a0, a2 = a0, a3 = a0;
#pragma unroll
      for (int s = 0; s < 3; s++) {
        short8 kf = *(const short8*)(&Ks[(ks * 16 + l16) * KS_STRIDE + s * 32 + quad * 8]);
        a0 = __builtin_amdgcn_mfma_f32_16x16x32_bf16(kf, qf[0][s], a0, 0, 0, 0);
        a1 = __builtin_amdgcn_mfma_f32_16x16x32_bf16(kf, qf[1][s], a1, 0, 0, 0);
        a2 = __builtin_amdgcn_mfma_f32_16x16x32_bf16(kf, qf[2][s], a2, 0, 0, 0);
        a3 = __builtin_amdgcn_mfma_f32_16x16x32_bf16(kf, qf[3][s], a3, 0, 0, 0);
      }
#pragma unroll
      for (int r = 0; r < 4; r++) {
        S[0][ks][r] = a0[r] * scale2;
        S[1][ks][r] = a1[r] * scale2;
        S[2][ks][r] = a2[r] * scale2;
        S[3][ks][r] = a3[r] * scale2;
      }
    }

    // softmax (log2): lane holds 16 scores for query l16 (+16*mi)
    float alpha[4];
#pragma unroll
    for (int mi = 0; mi < 4; mi++) {
      float tm = -INFINITY;
#pragma unroll
      for (int ks = 0; ks < 4; ks++)
#pragma unroll
        for (int r = 0; r < 4; r++) tm = fmaxf(tm, S[mi][ks][r]);
      tm = fmaxf(tm, __shfl_xor(tm, 16));
      tm = fmaxf(tm, __shfl_xor(tm, 32));
      float mnew = fmaxf(mrow[mi], tm);
      alpha[mi] = exp2f(mrow[mi] - mnew);
      mrow[mi] = mnew;
      float ps = 0.f;
#pragma unroll
      for (int ks = 0; ks < 4; ks++)
#pragma unroll
        for (int r = 0; r < 4; r++) {
          float p = exp2f(S[mi][ks][r] - mnew);
          ps += p;
          S[mi][ks][r] = p;
        }
      ps += __shfl_xor(ps, 16);
      ps += __shfl_xor(ps, 32);
      lrow[mi] = lrow[mi] * alpha[mi] + ps;
    }

    // redistribute alpha from query=l16 lanes to O-row lanes (row = quad*4+r)
    float aq[4][4];
#pragma unroll
    for (int mi = 0; mi < 4; mi++)
#pragma unroll
      for (int r = 0; r < 4; r++) aq[mi][r] = __shfl(alpha[mi], quad * 4 + r);
#pragma unroll
    for (int mi = 0; mi < 4; mi++)
#pragma unroll
      for (int nt = 0; nt < 5; nt++)
#pragma unroll
        for (int r = 0; r < 4; r++) Of[mi][nt][r] *= aq[mi][r];

    // two-pass PV over mi-pairs (Ps half-size; same-wave DS ordering, no barrier)
#pragma unroll
    for (int half = 0; half < 2; half++) {
#pragma unroll
      for (int mi2 = 0; mi2 < 2; mi2++) {
        int mi = half * 2 + mi2;
#pragma unroll
        for (int ks = 0; ks < 4; ks++) {
          union { short4v v; __hip_bfloat16 hh[4]; } pk;
#pragma unroll
          for (int r = 0; r < 4; r++) pk.hh[r] = __float2bfloat16(S[mi][ks][r]);
          *(short4v*)(&myPs[(mi2 * 16 + l16) * PS_STRIDE + ks * 16 + quad * 4]) = pk.v;
        }
      }
#pragma unroll
      for (int kstep = 0; kstep < 2; kstep++) {
        short8 pa0 = *(const short8*)(&myPs[(0 + l16) * PS_STRIDE + kstep * 32 + quad * 8]);
        short8 pa1 = *(const short8*)(&myPs[(16 + l16) * PS_STRIDE + kstep * 32 + quad * 8]);
#pragma unroll
        for (int nt = 0; nt < 5; nt++) {
          short8 vb = *(const short8*)(&Vt[(nt * 16 + l16) * VT_STRIDE + kstep * 32 + quad * 8]);
          Of[half * 2][nt]     = __builtin_amdgcn_mfma_f32_16x16x32_bf16(pa0, vb, Of[half * 2][nt], 0, 0, 0);
          Of[half * 2 + 1][nt] = __builtin_amdgcn_mfma_f32_16x16x32_bf16(pa1, vb, Of[half * 2 + 1][nt], 0, 0, 0);
        }
      }
    }
  }

  // store unnormalized partials (72 cols) + m,l
  const size_t pb = ((size_t)ksp * NHEADS + h) * L_TOK;
#pragma unroll
  for (int mi = 0; mi < 4; mi++) {
#pragma unroll
    for (int nt = 0; nt < 5; nt++) {
      int d = nt * 16 + l16;
      if (d < DHEAD) {
#pragma unroll
        for (int r = 0; r < 4; r++) {
          int q = qbase + mi * 16 + quad * 4 + r;
          Opart[(pb + q) * 72 + d] = __float2bfloat16(Of[mi][nt][r]);
        }
      }
    }
  }
  if (quad == 0) {   // lanes 0..15 hold stats for q = qbase + mi*16 + l16
#pragma unroll
    for (int mi = 0; mi < 4; mi++) {
      int q = qbase + mi * 16 + l16;
      Ml[(pb + q) * 2] = mrow[mi];
      Ml[(pb + q) * 2 + 1] = lrow[mi];
    }
  }
}

// ---------------------------------------------------------------------------
// flash-merge of the KSP partials (log2-domain m) -> ob[q][h*72+d] bf16
// ---------------------------------------------------------------------------
template <int KSP>
__global__ __launch_bounds__(256) void attn_merge(const __hip_bfloat16* __restrict__ Opart,
                                                  const float* __restrict__ Ml,
                                                  __hip_bfloat16* __restrict__ ob) {
  int idx = blockIdx.x * 256 + threadIdx.x;     // 8h * 4096q * 9ch
  int h = idx / (L_TOK * 9);
  int rem = idx - h * (L_TOK * 9);
  int q = rem / 9;
  int ch = rem - q * 9;
  size_t b[KSP];
  float m[KSP], l[KSP];
  float mx = -INFINITY;
#pragma unroll
  for (int s = 0; s < KSP; s++) {
    b[s] = ((size_t)s * NHEADS + h) * L_TOK + q;
    m[s] = Ml[b[s] * 2];
    l[s] = Ml[b[s] * 2 + 1];
    mx = fmaxf(mx, m[s]);
  }
  float w[KSP], denom = 0.f;
#pragma unroll
  for (int s = 0; s < KSP; s++) {
    w[s] = exp2f(m[s] - mx);
    denom += w[s] * l[s];
  }
  float inv = 1.f / denom;
  float acc[8] = {0, 0, 0, 0, 0, 0, 0, 0};
#pragma unroll
  for (int s = 0; s < KSP; s++) {
    short8 o = *(const short8*)(Opart + b[s] * 72 + ch * 8);
#pragma unroll
    for (int j = 0; j < 8; j++) {
      union { short ss; __hip_bfloat16 bb; } u;
      u.ss = o[j];
      acc[j] += w[s] * __bfloat162float(u.bb);
    }
  }
  __hip_bfloat16* dst = ob + (size_t)q * D_DIM + h * DHEAD + ch * 8;
#pragma unroll
  for (int j = 0; j < 8; j++) dst[j] = __float2bfloat16(acc[j] * inv);
}

// ---------------------------------------------------------------------------
extern "C" void kernel_launch(void* const* d_in, const int* in_sizes, int n_in,
                              void* d_out, int out_size, void* d_ws, size_t ws_size,
                              hipStream_t stream) {
  const float* fea    = (const float*)d_in[0];
  const float* w_qkv  = (const float*)d_in[1];
  const float* b_qkv  = (const float*)d_in[2];
  const float* w_out  = (const float*)d_in[3];
  const float* b_out  = (const float*)d_in[4];
  const float* conv_w = (const float*)d_in[5];
  float* out = (float*)d_out;

  // KSPLIT=6 needs 62,570,496 B of workspace; fall back to 4 (52.6 MB, proven)
  const size_t NEED6 = (size_t)(3760128 + 9437184 + 3145728 + 6 * 2359296) * 2
                       + (size_t)6 * 8 * 4096 * 2 * 4;
  const int KS = (ws_size >= NEED6) ? 6 : 4;

  __hip_bfloat16* xb    = (__hip_bfloat16*)d_ws;             // 4096*576
  __hip_bfloat16* WqkvT = xb + (size_t)L_TOK * D_DIM;        // 1728*576
  __hip_bfloat16* WoT   = WqkvT + (size_t)1728 * D_DIM;      // 576*576
  __hip_bfloat16* CwB   = WoT + (size_t)D_DIM * D_DIM;       // 128*576
  __hip_bfloat16* QKVb  = CwB + (size_t)128 * D_DIM;         // 3*HSZ (Q,K,V)
  __hip_bfloat16* VbT   = QKVb + 3 * HSZ;                    // HSZ
  __hip_bfloat16* Opart = VbT + HSZ;                         // KS*8*4096*72
  float* Ml = (float*)(Opart + (size_t)KS * NHEADS * L_TOK * 72);
  // ob aliases QKVb (dead after attn); xr aliases Opart (dead after merge)
  __hip_bfloat16* ob = QKVb;
  __hip_bfloat16* xr = Opart;

  unfold_kernel<<<dim3(64, 8), 256, 0, stream>>>(fea, xb);
  prep_weights<<<612, 256, 0, stream>>>(w_qkv, w_out, conv_w, WqkvT, WoT, CwB);

  gemm_mfma<0><<<dim3(32, 27), 256, 0, stream>>>(xb, WqkvT, b_qkv, nullptr, QKVb);
  transpose_v<<<dim3(64, 8), 256, 0, stream>>>(QKVb + 2 * HSZ, VbT);
  if (KS == 6) {
    attn_mfma<6><<<768, 256, 0, stream>>>(QKVb, QKVb + HSZ, VbT, Opart, Ml);
    attn_merge<6><<<1152, 256, 0, stream>>>(Opart, Ml, ob);
  } else {
    attn_mfma<4><<<512, 256, 0, stream>>>(QKVb, QKVb + HSZ, VbT, Opart, Ml);
    attn_merge<4><<<1152, 256, 0, stream>>>(Opart, Ml, ob);
  }
  gemm_mfma<1><<<dim3(32, 9), 256, 0, stream>>>(ob, WoT, b_out, xb, xr);
  final_small<<<dim3(64, 4), 256, 0, stream>>>(xr, CwB, out);
}

// Round 9
// 229.269 us; speedup vs baseline: 1.1217x; 1.1217x over previous
//
#include <hip/hip_runtime.h>
#include <hip/hip_bf16.h>
#include <math.h>

#define L_TOK 4096
#define D_DIM 576
#define NHEADS 8
#define DHEAD 72
#define DPAD 96
#define HSZ ((size_t)NHEADS * L_TOK * DPAD)   // elems per head-padded tensor
#define KSPLIT 4
#define LOG2E 1.4426950408889634f

typedef __attribute__((ext_vector_type(8))) short short8;
typedef __attribute__((ext_vector_type(4))) short short4v;
typedef __attribute__((ext_vector_type(4))) float float4v;

union F4S8 {
  float4 f4;
  short8 s8;
  __hip_bfloat16 h[8];
};

// ---------------------------------------------------------------------------
// fused pre-pass: unfold (512 blocks) + w_qkv^T (243) + w_out^T (81) +
// conv_w cvt (288) = 1124 blocks, one launch.
// ---------------------------------------------------------------------------
__device__ inline void tc_body(const float* __restrict__ src,
                               __hip_bfloat16* __restrict__ dst, int R, int C,
                               int bi, int bj, int t, __hip_bfloat16* Ts) {
  const int col = t & 63, row4 = t >> 6;
#pragma unroll
  for (int u = 0; u < 16; u++) {
    int r = u * 4 + row4;
    Ts[r * 68 + col] = __float2bfloat16(src[(size_t)(bj * 64 + r) * C + bi * 64 + col]);
  }
  __syncthreads();
#pragma unroll
  for (int u = 0; u < 16; u++) {
    int c = u * 4 + row4;
    dst[(size_t)(bi * 64 + c) * R + bj * 64 + col] = Ts[col * 68 + c];
  }
}

__global__ __launch_bounds__(256) void prep_all(const float* __restrict__ fea,
                                                const float* __restrict__ w_qkv,
                                                const float* __restrict__ w_out,
                                                const float* __restrict__ conv_w,
                                                __hip_bfloat16* __restrict__ xb,
                                                __hip_bfloat16* __restrict__ WqkvT,
                                                __hip_bfloat16* __restrict__ WoT,
                                                __hip_bfloat16* __restrict__ CwB) {
  __shared__ float Shm[3120];        // 12480 B; reused as Ts (8704 B)
  const int b = blockIdx.x;
  const int t = threadIdx.x;
  if (b < 512) {
    // unfold 3x3 s2 p1 -> xb [4096][576], LDS-tiled (coalesced both sides)
    float* Lf = Shm;                 // [24][130]
    const int ho = b & 63;
    const int c0 = (b >> 6) * 8;
    for (int e = t; e < 3072; e += 256) {
      int c = e / 384;
      int rr = (e / 128) % 3;
      int w = e & 127;
      int h = 2 * ho + rr - 1;
      float v = 0.f;
      if ((unsigned)h < 128u) v = fea[(size_t)(c0 + c) * 16384 + h * 128 + w];
      Lf[(c * 3 + rr) * 130 + w + 1] = v;
    }
    if (t < 24) { Lf[t * 130] = 0.f; Lf[t * 130 + 129] = 0.f; }
    __syncthreads();
    for (int e = t; e < 576; e += 256) {
      int wo = e / 9, ch = e - wo * 9;
      F4S8 u;
#pragma unroll
      for (int j = 0; j < 8; j++) {
        int dd = ch * 8 + j;
        int c = dd / 9, k = dd - c * 9;
        int ki = k / 3, kj = k - ki * 3;
        u.h[j] = __float2bfloat16(Lf[(c * 3 + ki) * 130 + 2 * wo + kj]);
      }
      *(float4*)(xb + (size_t)(ho * 64 + wo) * D_DIM + c0 * 9 + ch * 8) = u.f4;
    }
  } else if (b < 755) {
    int bb = b - 512;
    tc_body(w_qkv, WqkvT, D_DIM, 1728, bb % 27, bb / 27, t, (__hip_bfloat16*)Shm);
  } else if (b < 836) {
    int bb = b - 755;
    tc_body(w_out, WoT, D_DIM, D_DIM, bb % 9, bb / 9, t, (__hip_bfloat16*)Shm);
  } else {
    int i = (b - 836) * 256 + t;
    CwB[i] = __float2bfloat16(conv_w[i]);
  }
}

// ---------------------------------------------------------------------------
// bf16 MFMA GEMM: C[M][N] = A[M][576] @ Bt[N][576]^T (+epilogue)
// BM=128, BN=64, BK=64; 4 waves 2x2.
// EPI 0: QKV. Q,K -> [h][L][96] coalesced; V -> V^T [h][96][L] via LDS
//        transpose tile (Ls[64][136], once per WG, float4 stores).
// EPI 1: oproj (+bias +residual -> bf16)
// ---------------------------------------------------------------------------
template <int EPI>
__global__ __launch_bounds__(256) void gemm_mfma(const __hip_bfloat16* __restrict__ A,
                                                 const __hip_bfloat16* __restrict__ Bt,
                                                 const float* __restrict__ bias,
                                                 const __hip_bfloat16* __restrict__ resid,
                                                 __hip_bfloat16* __restrict__ outB,
                                                 __hip_bfloat16* __restrict__ outB2) {
  constexpr int K = D_DIM;
  __shared__ __align__(16) __hip_bfloat16 As[128 * 72];
  __shared__ __align__(16) __hip_bfloat16 Bs[64 * 72];
  __shared__ __align__(16) __hip_bfloat16 Ls[EPI == 0 ? 64 * 136 : 1];
  const int t = threadIdx.x;
  const int wave = t >> 6, lane = t & 63, quad = lane >> 4, l16 = lane & 15;
  const int wm = (wave & 2) * 32;   // 0 or 64
  const int wn = (wave & 1) * 32;   // 0 or 32
  const int m0 = blockIdx.x * 128, n0 = blockIdx.y * 64;

  float4v acc[4][2];
#pragma unroll
  for (int i = 0; i < 4; i++)
#pragma unroll
    for (int j = 0; j < 2; j++) acc[i][j] = (float4v){0.f, 0.f, 0.f, 0.f};

  const int arow = t >> 3, ach = t & 7;
  for (int k0 = 0; k0 < K; k0 += 64) {
    __syncthreads();
#pragma unroll
    for (int u = 0; u < 4; u++) {
      int row = u * 32 + arow;
      *(float4*)(&As[row * 72 + ach * 8]) =
          *(const float4*)(A + (size_t)(m0 + row) * K + k0 + ach * 8);
    }
#pragma unroll
    for (int u = 0; u < 2; u++) {
      int row = u * 32 + arow;
      *(float4*)(&Bs[row * 72 + ach * 8]) =
          *(const float4*)(Bt + (size_t)(n0 + row) * K + k0 + ach * 8);
    }
    __syncthreads();
    short8 af[4][2], bfr[2][2];
#pragma unroll
    for (int i = 0; i < 4; i++)
#pragma unroll
      for (int s = 0; s < 2; s++)
        af[i][s] = *(const short8*)(&As[(wm + i * 16 + l16) * 72 + s * 32 + quad * 8]);
#pragma unroll
    for (int j = 0; j < 2; j++)
#pragma unroll
      for (int s = 0; s < 2; s++)
        bfr[j][s] = *(const short8*)(&Bs[(wn + j * 16 + l16) * 72 + s * 32 + quad * 8]);
#pragma unroll
    for (int i = 0; i < 4; i++)
#pragma unroll
      for (int j = 0; j < 2; j++) {
        acc[i][j] = __builtin_amdgcn_mfma_f32_16x16x32_bf16(af[i][0], bfr[j][0], acc[i][j], 0, 0, 0);
        acc[i][j] = __builtin_amdgcn_mfma_f32_16x16x32_bf16(af[i][1], bfr[j][1], acc[i][j], 0, 0, 0);
      }
  }

  // epilogue; C/D layout: col = l16 (n), row = quad*4 + r (m)
  if (EPI == 0) {
    const int part = n0 / D_DIM;          // tile lies in exactly one of Q/K/V
    if (part < 2) {
      __hip_bfloat16* dst = outB + (size_t)part * HSZ;
#pragma unroll
      for (int j = 0; j < 2; j++) {
        int ng = n0 + wn + j * 16 + l16;
        float bv = bias[ng];
        int rem = ng - part * D_DIM;
        int h = rem / DHEAD;
        int d = rem - h * DHEAD;
#pragma unroll
        for (int i = 0; i < 4; i++) {
          int mb = m0 + wm + i * 16 + quad * 4;
#pragma unroll
          for (int r = 0; r < 4; r++)
            dst[((size_t)h * L_TOK + mb + r) * DPAD + d] = __float2bfloat16(acc[i][j][r] + bv);
        }
      }
    } else {
      // V: transpose via LDS, store V^T [h][96][L] with float4 rows
      const int n0rel = n0 - 2 * D_DIM;
#pragma unroll
      for (int j = 0; j < 2; j++) {
        int nloc = wn + j * 16 + l16;
        float bv = bias[n0 + nloc];
#pragma unroll
        for (int i = 0; i < 4; i++) {
          int mloc = wm + i * 16 + quad * 4;
#pragma unroll
          for (int r = 0; r < 4; r++)
            Ls[nloc * 136 + mloc + r] = __float2bfloat16(acc[i][j][r] + bv);
        }
      }
      __syncthreads();
      for (int e = t; e < 1024; e += 256) {
        int row = e >> 4, ch = e & 15;
        int ng = n0rel + row;
        int hh = ng / DHEAD, dd = ng - hh * DHEAD;
        *(float4*)(outB2 + ((size_t)hh * DPAD + dd) * L_TOK + m0 + ch * 8) =
            *(const float4*)(&Ls[row * 136 + ch * 8]);
      }
    }
  } else {
#pragma unroll
    for (int j = 0; j < 2; j++) {
      int ng = n0 + wn + j * 16 + l16;
      float bv = bias[ng];
#pragma unroll
      for (int i = 0; i < 4; i++) {
        int mb = m0 + wm + i * 16 + quad * 4;
#pragma unroll
        for (int r = 0; r < 4; r++) {
          size_t idx = (size_t)(mb + r) * D_DIM + ng;
          float v = acc[i][j][r] + bv + __bfloat162float(resid[idx]);
          outB[idx] = __float2bfloat16(v);
        }
      }
    }
  }
}

// ---------------------------------------------------------------------------
// final conv GEMM + SiLU: BM=64, BN=32, grid (64,4)=256 WGs.
// ---------------------------------------------------------------------------
__global__ __launch_bounds__(256) void final_small(const __hip_bfloat16* __restrict__ A,
                                                   const __hip_bfloat16* __restrict__ Bt,
                                                   float* __restrict__ out) {
  __shared__ __align__(16) __hip_bfloat16 As[64 * 72];
  __shared__ __align__(16) __hip_bfloat16 Bs[32 * 72];
  const int t = threadIdx.x;
  const int wave = t >> 6, lane = t & 63, quad = lane >> 4, l16 = lane & 15;
  const int wm = (wave & 2) * 16;   // 0 or 32
  const int wn = (wave & 1) * 16;   // 0 or 16
  const int m0 = blockIdx.x * 64, n0 = blockIdx.y * 32;

  float4v acc[2];
  acc[0] = (float4v){0.f, 0.f, 0.f, 0.f};
  acc[1] = (float4v){0.f, 0.f, 0.f, 0.f};

  const int arow = t >> 3, ach = t & 7;
  for (int k0 = 0; k0 < D_DIM; k0 += 64) {
    __syncthreads();
#pragma unroll
    for (int u = 0; u < 2; u++) {
      int row = u * 32 + arow;
      *(float4*)(&As[row * 72 + ach * 8]) =
          *(const float4*)(A + (size_t)(m0 + row) * D_DIM + k0 + ach * 8);
    }
    if (arow < 32)
      *(float4*)(&Bs[arow * 72 + ach * 8]) =
          *(const float4*)(Bt + (size_t)(n0 + arow) * D_DIM + k0 + ach * 8);
    __syncthreads();
    short8 af[2][2], bfr[2];
#pragma unroll
    for (int i = 0; i < 2; i++)
#pragma unroll
      for (int s = 0; s < 2; s++)
        af[i][s] = *(const short8*)(&As[(wm + i * 16 + l16) * 72 + s * 32 + quad * 8]);
#pragma unroll
    for (int s = 0; s < 2; s++)
      bfr[s] = *(const short8*)(&Bs[(wn + l16) * 72 + s * 32 + quad * 8]);
#pragma unroll
    for (int i = 0; i < 2; i++) {
      acc[i] = __builtin_amdgcn_mfma_f32_16x16x32_bf16(af[i][0], bfr[0], acc[i], 0, 0, 0);
      acc[i] = __builtin_amdgcn_mfma_f32_16x16x32_bf16(af[i][1], bfr[1], acc[i], 0, 0, 0);
    }
  }
  const int oc = n0 + wn + l16;
#pragma unroll
  for (int i = 0; i < 2; i++) {
    int mb = m0 + wm + i * 16 + quad * 4;
#pragma unroll
    for (int r = 0; r < 4; r++) {
      float v = acc[i][r];
      float sg = 1.f / (1.f + __expf(-v));
      out[(size_t)oc * L_TOK + mb + r] = v * sg;
    }
  }
}

// ---------------------------------------------------------------------------
// bf16 MFMA flash attention — R7 structure (best known: 93 us).
// S^T formulation, LDS-staged K/V, 64 q/wave, KSPLIT=4, grid 512 = 2 WG/CU.
// Full Ps (36.9 KB), single-pass PV. Softmax in log2 domain.
// ---------------------------------------------------------------------------
#define KS_STRIDE 104
#define VT_STRIDE 72
#define PS_STRIDE 72

__global__ __launch_bounds__(256, 2) void attn_mfma(const __hip_bfloat16* __restrict__ Qb,
                                                    const __hip_bfloat16* __restrict__ Kb,
                                                    const __hip_bfloat16* __restrict__ VbT,
                                                    __hip_bfloat16* __restrict__ Opart,
                                                    float* __restrict__ Ml) {
  __shared__ __align__(16) __hip_bfloat16 Ks[64 * KS_STRIDE];      // 13312 B
  __shared__ __align__(16) __hip_bfloat16 Vt[80 * VT_STRIDE];      // 11520 B
  __shared__ __align__(16) __hip_bfloat16 Ps[4 * 64 * PS_STRIDE];  // 36864 B

  const int bid = blockIdx.x;
  const int h = bid & 7;                  // head -> XCD affinity
  const int rest = bid >> 3;
  const int ksp = rest & 3;
  const int qblk = rest >> 2;             // 0..15
  const int t = threadIdx.x;
  const int wave = t >> 6;
  const int lane = t & 63;
  const int quad = lane >> 4;
  const int l16 = lane & 15;

  const __hip_bfloat16* Qh = Qb + (size_t)h * L_TOK * DPAD;
  const __hip_bfloat16* Kh = Kb + (size_t)h * L_TOK * DPAD;
  const __hip_bfloat16* VhT = VbT + (size_t)h * DPAD * L_TOK;

  // Q as MFMA B operand: lane holds Q[q=l16][d=s*32+quad*8+j]; d>=72 pad -> 0
  const int qbase = qblk * 256 + wave * 64;
  short8 qf[4][3];
#pragma unroll
  for (int mi = 0; mi < 4; mi++) {
#pragma unroll
    for (int s = 0; s < 3; s++) {
      if (s == 2 && quad >= 1) {
        qf[mi][s] = (short8){0, 0, 0, 0, 0, 0, 0, 0};
      } else {
        qf[mi][s] = *(const short8*)(Qh + (size_t)(qbase + mi * 16 + l16) * DPAD + s * 32 + quad * 8);
      }
    }
  }

  // one-time zero of Ks pad cols 72..95 (stale-LDS NaN guard)
  const float4 zero4 = {0.f, 0.f, 0.f, 0.f};
  if (t < 192) {
    int row = t / 3, ch = 9 + t % 3;
    *(float4*)(&Ks[row * KS_STRIDE + ch * 8]) = zero4;
  }

  float4v Of[4][5];
#pragma unroll
  for (int mi = 0; mi < 4; mi++)
#pragma unroll
    for (int nt = 0; nt < 5; nt++) Of[mi][nt] = (float4v){0.f, 0.f, 0.f, 0.f};
  float mrow[4] = {-INFINITY, -INFINITY, -INFINITY, -INFINITY};  // log2 domain
  float lrow[4] = {0.f, 0.f, 0.f, 0.f};
  const float scale2 = 0.11785113019775792f * LOG2E;  // 72^-0.5 * log2(e)

  __hip_bfloat16* myPs = Ps + wave * 64 * PS_STRIDE;
  const int kstart = ksp * 1024;            // 16 tiles * 64 keys

  for (int kt = 0; kt < 16; kt++) {
    const int kbase = kstart + kt * 64;
    __syncthreads();  // prior tile's K/V reads complete

    // stage K tile [64 keys][d<72] : 576 chunks
    for (int e = t; e < 576; e += 256) {
      int row = e / 9, ch = e - row * 9;
      *(float4*)(&Ks[row * KS_STRIDE + ch * 8]) =
          *(const float4*)(Kh + (size_t)(kbase + row) * DPAD + ch * 8);
    }
    // stage V^T tile [80 d][64 keys] (d>=72 garbage but finite)
    for (int e = t; e < 640; e += 256) {
      int d = e >> 3, ch = e & 7;
      *(float4*)(&Vt[d * VT_STRIDE + ch * 8]) =
          *(const float4*)(VhT + (size_t)d * L_TOK + kbase + ch * 8);
    }
    __syncthreads();

    // S^T = K Q^T (log2-scaled): A = K-frag shared across 4 q-frags
    float4v S[4][4];
#pragma unroll
    for (int ks = 0; ks < 4; ks++) {
      float4v a0 = (float4v){0.f, 0.f, 0.f, 0.f};
      float4v a1 = a0, a2 = a0, a3 = a0;
#pragma unroll
      for (int s = 0; s < 3; s++) {
        short8 kf = *(const short8*)(&Ks[(ks * 16 + l16) * KS_STRIDE + s * 32 + quad * 8]);
        a0 = __builtin_amdgcn_mfma_f32_16x16x32_bf16(kf, qf[0][s], a0, 0, 0, 0);
        a1 = __builtin_amdgcn_mfma_f32_16x16x32_bf16(kf, qf[1][s], a1, 0, 0, 0);
        a2 = __builtin_amdgcn_mfma_f32_16x16x32_bf16(kf, qf[2][s], a2, 0, 0, 0);
        a3 = __builtin_amdgcn_mfma_f32_16x16x32_bf16(kf, qf[3][s], a3, 0, 0, 0);
      }
#pragma unroll
      for (int r = 0; r < 4; r++) {
        S[0][ks][r] = a0[r] * scale2;
        S[1][ks][r] = a1[r] * scale2;
        S[2][ks][r] = a2[r] * scale2;
        S[3][ks][r] = a3[r] * scale2;
      }
    }

    // softmax (log2 domain): lane holds 16 scores for query l16 (+16*mi)
    float alpha[4];
#pragma unroll
    for (int mi = 0; mi < 4; mi++) {
      float tm = -INFINITY;
#pragma unroll
      for (int ks = 0; ks < 4; ks++)
#pragma unroll
        for (int r = 0; r < 4; r++) tm = fmaxf(tm, S[mi][ks][r]);
      tm = fmaxf(tm, __shfl_xor(tm, 16));
      tm = fmaxf(tm, __shfl_xor(tm, 32));
      float mnew = fmaxf(mrow[mi], tm);
      alpha[mi] = exp2f(mrow[mi] - mnew);
      mrow[mi] = mnew;
      float ps = 0.f;
#pragma unroll
      for (int ks = 0; ks < 4; ks++)
#pragma unroll
        for (int r = 0; r < 4; r++) {
          float p = exp2f(S[mi][ks][r] - mnew);
          ps += p;
          S[mi][ks][r] = p;
        }
      ps += __shfl_xor(ps, 16);
      ps += __shfl_xor(ps, 32);
      lrow[mi] = lrow[mi] * alpha[mi] + ps;
    }

    // P writes: Ps[q][key], 4 consecutive keys packed per ds_write_b64
#pragma unroll
    for (int mi = 0; mi < 4; mi++) {
#pragma unroll
      for (int ks = 0; ks < 4; ks++) {
        union { short4v v; __hip_bfloat16 hh[4]; } pk;
#pragma unroll
        for (int r = 0; r < 4; r++) pk.hh[r] = __float2bfloat16(S[mi][ks][r]);
        *(short4v*)(&myPs[(mi * 16 + l16) * PS_STRIDE + ks * 16 + quad * 4]) = pk.v;
      }
    }

    // redistribute alpha from query=l16 lanes to O-row lanes (row = quad*4+r)
    float aq[4][4];
#pragma unroll
    for (int mi = 0; mi < 4; mi++)
#pragma unroll
      for (int r = 0; r < 4; r++) aq[mi][r] = __shfl(alpha[mi], quad * 4 + r);
#pragma unroll
    for (int mi = 0; mi < 4; mi++)
#pragma unroll
      for (int nt = 0; nt < 5; nt++)
#pragma unroll
        for (int r = 0; r < 4; r++) Of[mi][nt][r] *= aq[mi][r];

    // O += P V : A = P (per-wave LDS, same-wave in-order), B = V-frag
#pragma unroll
    for (int kstep = 0; kstep < 2; kstep++) {
      short8 pa[4];
#pragma unroll
      for (int mi = 0; mi < 4; mi++)
        pa[mi] = *(const short8*)(&myPs[(mi * 16 + l16) * PS_STRIDE + kstep * 32 + quad * 8]);
#pragma unroll
      for (int nt = 0; nt < 5; nt++) {
        short8 vb = *(const short8*)(&Vt[(nt * 16 + l16) * VT_STRIDE + kstep * 32 + quad * 8]);
        Of[0][nt] = __builtin_amdgcn_mfma_f32_16x16x32_bf16(pa[0], vb, Of[0][nt], 0, 0, 0);
        Of[1][nt] = __builtin_amdgcn_mfma_f32_16x16x32_bf16(pa[1], vb, Of[1][nt], 0, 0, 0);
        Of[2][nt] = __builtin_amdgcn_mfma_f32_16x16x32_bf16(pa[2], vb, Of[2][nt], 0, 0, 0);
        Of[3][nt] = __builtin_amdgcn_mfma_f32_16x16x32_bf16(pa[3], vb, Of[3][nt], 0, 0, 0);
      }
    }
  }

  // store unnormalized partials (72 cols) + m,l
  const size_t pb = ((size_t)ksp * NHEADS + h) * L_TOK;
#pragma unroll
  for (int mi = 0; mi < 4; mi++) {
#pragma unroll
    for (int nt = 0; nt < 5; nt++) {
      int d = nt * 16 + l16;
      if (d < DHEAD) {
#pragma unroll
        for (int r = 0; r < 4; r++) {
          int q = qbase + mi * 16 + quad * 4 + r;
          Opart[(pb + q) * 72 + d] = __float2bfloat16(Of[mi][nt][r]);
        }
      }
    }
  }
  if (quad == 0) {   // lanes 0..15 hold stats for q = qbase + mi*16 + l16
#pragma unroll
    for (int mi = 0; mi < 4; mi++) {
      int q = qbase + mi * 16 + l16;
      Ml[(pb + q) * 2] = mrow[mi];
      Ml[(pb + q) * 2 + 1] = lrow[mi];
    }
  }
}

// ---------------------------------------------------------------------------
// flash-merge of the KSPLIT partials (log2-domain m) -> ob[q][h*72+d] bf16
// ---------------------------------------------------------------------------
__global__ __launch_bounds__(256) void attn_merge(const __hip_bfloat16* __restrict__ Opart,
                                                  const float* __restrict__ Ml,
                                                  __hip_bfloat16* __restrict__ ob) {
  int idx = blockIdx.x * 256 + threadIdx.x;     // 8h * 4096q * 9ch
  int h = idx / (L_TOK * 9);
  int rem = idx - h * (L_TOK * 9);
  int q = rem / 9;
  int ch = rem - q * 9;
  size_t b[KSPLIT];
  float m[KSPLIT], l[KSPLIT];
  float mx = -INFINITY;
#pragma unroll
  for (int s = 0; s < KSPLIT; s++) {
    b[s] = ((size_t)s * NHEADS + h) * L_TOK + q;
    m[s] = Ml[b[s] * 2];
    l[s] = Ml[b[s] * 2 + 1];
    mx = fmaxf(mx, m[s]);
  }
  float w[KSPLIT], denom = 0.f;
#pragma unroll
  for (int s = 0; s < KSPLIT; s++) {
    w[s] = exp2f(m[s] - mx);
    denom += w[s] * l[s];
  }
  float inv = 1.f / denom;
  float acc[8] = {0, 0, 0, 0, 0, 0, 0, 0};
#pragma unroll
  for (int s = 0; s < KSPLIT; s++) {
    short8 o = *(const short8*)(Opart + b[s] * 72 + ch * 8);
#pragma unroll
    for (int j = 0; j < 8; j++) {
      union { short ss; __hip_bfloat16 bb; } u;
      u.ss = o[j];
      acc[j] += w[s] * __bfloat162float(u.bb);
    }
  }
  __hip_bfloat16* dst = ob + (size_t)q * D_DIM + h * DHEAD + ch * 8;
#pragma unroll
  for (int j = 0; j < 8; j++) dst[j] = __float2bfloat16(acc[j] * inv);
}

// ---------------------------------------------------------------------------
extern "C" void kernel_launch(void* const* d_in, const int* in_sizes, int n_in,
                              void* d_out, int out_size, void* d_ws, size_t ws_size,
                              hipStream_t stream) {
  const float* fea    = (const float*)d_in[0];
  const float* w_qkv  = (const float*)d_in[1];
  const float* b_qkv  = (const float*)d_in[2];
  const float* w_out  = (const float*)d_in[3];
  const float* b_out  = (const float*)d_in[4];
  const float* conv_w = (const float*)d_in[5];
  float* out = (float*)d_out;

  __hip_bfloat16* xb    = (__hip_bfloat16*)d_ws;             // 4096*576
  __hip_bfloat16* WqkvT = xb + (size_t)L_TOK * D_DIM;        // 1728*576
  __hip_bfloat16* WoT   = WqkvT + (size_t)1728 * D_DIM;      // 576*576
  __hip_bfloat16* CwB   = WoT + (size_t)D_DIM * D_DIM;       // 128*576
  __hip_bfloat16* QKb   = CwB + (size_t)128 * D_DIM;         // 2*HSZ (Q,K)
  __hip_bfloat16* VbT   = QKb + 2 * HSZ;                     // HSZ (V^T)
  __hip_bfloat16* Opart = VbT + HSZ;                         // KSPLIT*8*4096*72
  float* Ml = (float*)(Opart + (size_t)KSPLIT * NHEADS * L_TOK * 72);
  // ob aliases QKb (Q,K dead after attn); xr aliases Opart (dead after merge)
  __hip_bfloat16* ob = QKb;
  __hip_bfloat16* xr = Opart;

  prep_all<<<1124, 256, 0, stream>>>(fea, w_qkv, w_out, conv_w, xb, WqkvT, WoT, CwB);
  gemm_mfma<0><<<dim3(32, 27), 256, 0, stream>>>(xb, WqkvT, b_qkv, nullptr, QKb, VbT);
  attn_mfma<<<512, 256, 0, stream>>>(QKb, QKb + HSZ, VbT, Opart, Ml);
  attn_merge<<<1152, 256, 0, stream>>>(Opart, Ml, ob);
  gemm_mfma<1><<<dim3(32, 9), 256, 0, stream>>>(ob, WoT, b_out, xb, xr, nullptr);
  final_small<<<dim3(64, 4), 256, 0, stream>>>(xr, CwB, out);
}

// Round 10
// 223.090 us; speedup vs baseline: 1.1527x; 1.0277x over previous
//
#include <hip/hip_runtime.h>
#include <hip/hip_bf16.h>
#include <math.h>

#define L_TOK 4096
#define D_DIM 576
#define NHEADS 8
#define DHEAD 72
#define DPAD 96
#define HSZ ((size_t)NHEADS * L_TOK * DPAD)   // elems per head-padded tensor
#define KSPLIT 4
#define LOG2E 1.4426950408889634f

typedef __attribute__((ext_vector_type(8))) short short8;
typedef __attribute__((ext_vector_type(4))) short short4v;
typedef __attribute__((ext_vector_type(4))) float float4v;

union F4S8 {
  float4 f4;
  short8 s8;
  __hip_bfloat16 h[8];
};

// ---------------------------------------------------------------------------
// fused pre-pass: unfold (512 blocks) + w_qkv^T (243) + w_out^T (81) +
// conv_w cvt (288) = 1124 blocks, one launch.
// ---------------------------------------------------------------------------
__device__ inline void tc_body(const float* __restrict__ src,
                               __hip_bfloat16* __restrict__ dst, int R, int C,
                               int bi, int bj, int t, __hip_bfloat16* Ts) {
  const int col = t & 63, row4 = t >> 6;
#pragma unroll
  for (int u = 0; u < 16; u++) {
    int r = u * 4 + row4;
    Ts[r * 68 + col] = __float2bfloat16(src[(size_t)(bj * 64 + r) * C + bi * 64 + col]);
  }
  __syncthreads();
#pragma unroll
  for (int u = 0; u < 16; u++) {
    int c = u * 4 + row4;
    dst[(size_t)(bi * 64 + c) * R + bj * 64 + col] = Ts[col * 68 + c];
  }
}

__global__ __launch_bounds__(256) void prep_all(const float* __restrict__ fea,
                                                const float* __restrict__ w_qkv,
                                                const float* __restrict__ w_out,
                                                const float* __restrict__ conv_w,
                                                __hip_bfloat16* __restrict__ xb,
                                                __hip_bfloat16* __restrict__ WqkvT,
                                                __hip_bfloat16* __restrict__ WoT,
                                                __hip_bfloat16* __restrict__ CwB) {
  __shared__ float Shm[3120];        // 12480 B; reused as Ts (8704 B)
  const int b = blockIdx.x;
  const int t = threadIdx.x;
  if (b < 512) {
    // unfold 3x3 s2 p1 -> xb [4096][576], LDS-tiled (coalesced both sides)
    float* Lf = Shm;                 // [24][130]
    const int ho = b & 63;
    const int c0 = (b >> 6) * 8;
    for (int e = t; e < 3072; e += 256) {
      int c = e / 384;
      int rr = (e / 128) % 3;
      int w = e & 127;
      int h = 2 * ho + rr - 1;
      float v = 0.f;
      if ((unsigned)h < 128u) v = fea[(size_t)(c0 + c) * 16384 + h * 128 + w];
      Lf[(c * 3 + rr) * 130 + w + 1] = v;
    }
    if (t < 24) { Lf[t * 130] = 0.f; Lf[t * 130 + 129] = 0.f; }
    __syncthreads();
    for (int e = t; e < 576; e += 256) {
      int wo = e / 9, ch = e - wo * 9;
      F4S8 u;
#pragma unroll
      for (int j = 0; j < 8; j++) {
        int dd = ch * 8 + j;
        int c = dd / 9, k = dd - c * 9;
        int ki = k / 3, kj = k - ki * 3;
        u.h[j] = __float2bfloat16(Lf[(c * 3 + ki) * 130 + 2 * wo + kj]);
      }
      *(float4*)(xb + (size_t)(ho * 64 + wo) * D_DIM + c0 * 9 + ch * 8) = u.f4;
    }
  } else if (b < 755) {
    int bb = b - 512;
    tc_body(w_qkv, WqkvT, D_DIM, 1728, bb % 27, bb / 27, t, (__hip_bfloat16*)Shm);
  } else if (b < 836) {
    int bb = b - 755;
    tc_body(w_out, WoT, D_DIM, D_DIM, bb % 9, bb / 9, t, (__hip_bfloat16*)Shm);
  } else {
    int i = (b - 836) * 256 + t;
    CwB[i] = __float2bfloat16(conv_w[i]);
  }
}

// ---------------------------------------------------------------------------
// bf16 MFMA GEMM: C[M][N] = A[M][576] @ Bt[N][576]^T (+epilogue)
// BM=128, BN=64, BK=64; 4 waves 2x2.
// EPI 0: QKV. Q,K -> [h][L][96] coalesced; V -> V^T [h][96][L] via LDS
//        transpose tile (Ls[64][136], once per WG, float4 stores).
// EPI 1: oproj (+bias +residual -> bf16)
// ---------------------------------------------------------------------------
template <int EPI>
__global__ __launch_bounds__(256) void gemm_mfma(const __hip_bfloat16* __restrict__ A,
                                                 const __hip_bfloat16* __restrict__ Bt,
                                                 const float* __restrict__ bias,
                                                 const __hip_bfloat16* __restrict__ resid,
                                                 __hip_bfloat16* __restrict__ outB,
                                                 __hip_bfloat16* __restrict__ outB2) {
  constexpr int K = D_DIM;
  __shared__ __align__(16) __hip_bfloat16 As[128 * 72];
  __shared__ __align__(16) __hip_bfloat16 Bs[64 * 72];
  __shared__ __align__(16) __hip_bfloat16 Ls[EPI == 0 ? 64 * 136 : 1];
  const int t = threadIdx.x;
  const int wave = t >> 6, lane = t & 63, quad = lane >> 4, l16 = lane & 15;
  const int wm = (wave & 2) * 32;   // 0 or 64
  const int wn = (wave & 1) * 32;   // 0 or 32
  const int m0 = blockIdx.x * 128, n0 = blockIdx.y * 64;

  float4v acc[4][2];
#pragma unroll
  for (int i = 0; i < 4; i++)
#pragma unroll
    for (int j = 0; j < 2; j++) acc[i][j] = (float4v){0.f, 0.f, 0.f, 0.f};

  const int arow = t >> 3, ach = t & 7;
  for (int k0 = 0; k0 < K; k0 += 64) {
    __syncthreads();
#pragma unroll
    for (int u = 0; u < 4; u++) {
      int row = u * 32 + arow;
      *(float4*)(&As[row * 72 + ach * 8]) =
          *(const float4*)(A + (size_t)(m0 + row) * K + k0 + ach * 8);
    }
#pragma unroll
    for (int u = 0; u < 2; u++) {
      int row = u * 32 + arow;
      *(float4*)(&Bs[row * 72 + ach * 8]) =
          *(const float4*)(Bt + (size_t)(n0 + row) * K + k0 + ach * 8);
    }
    __syncthreads();
    short8 af[4][2], bfr[2][2];
#pragma unroll
    for (int i = 0; i < 4; i++)
#pragma unroll
      for (int s = 0; s < 2; s++)
        af[i][s] = *(const short8*)(&As[(wm + i * 16 + l16) * 72 + s * 32 + quad * 8]);
#pragma unroll
    for (int j = 0; j < 2; j++)
#pragma unroll
      for (int s = 0; s < 2; s++)
        bfr[j][s] = *(const short8*)(&Bs[(wn + j * 16 + l16) * 72 + s * 32 + quad * 8]);
#pragma unroll
    for (int i = 0; i < 4; i++)
#pragma unroll
      for (int j = 0; j < 2; j++) {
        acc[i][j] = __builtin_amdgcn_mfma_f32_16x16x32_bf16(af[i][0], bfr[j][0], acc[i][j], 0, 0, 0);
        acc[i][j] = __builtin_amdgcn_mfma_f32_16x16x32_bf16(af[i][1], bfr[j][1], acc[i][j], 0, 0, 0);
      }
  }

  // epilogue; C/D layout: col = l16 (n), row = quad*4 + r (m)
  if (EPI == 0) {
    const int part = n0 / D_DIM;          // tile lies in exactly one of Q/K/V
    if (part < 2) {
      __hip_bfloat16* dst = outB + (size_t)part * HSZ;
#pragma unroll
      for (int j = 0; j < 2; j++) {
        int ng = n0 + wn + j * 16 + l16;
        float bv = bias[ng];
        int rem = ng - part * D_DIM;
        int h = rem / DHEAD;
        int d = rem - h * DHEAD;
#pragma unroll
        for (int i = 0; i < 4; i++) {
          int mb = m0 + wm + i * 16 + quad * 4;
#pragma unroll
          for (int r = 0; r < 4; r++)
            dst[((size_t)h * L_TOK + mb + r) * DPAD + d] = __float2bfloat16(acc[i][j][r] + bv);
        }
      }
    } else {
      // V: transpose via LDS, store V^T [h][96][L] with float4 rows
      const int n0rel = n0 - 2 * D_DIM;
#pragma unroll
      for (int j = 0; j < 2; j++) {
        int nloc = wn + j * 16 + l16;
        float bv = bias[n0 + nloc];
#pragma unroll
        for (int i = 0; i < 4; i++) {
          int mloc = wm + i * 16 + quad * 4;
#pragma unroll
          for (int r = 0; r < 4; r++)
            Ls[nloc * 136 + mloc + r] = __float2bfloat16(acc[i][j][r] + bv);
        }
      }
      __syncthreads();
      for (int e = t; e < 1024; e += 256) {
        int row = e >> 4, ch = e & 15;
        int ng = n0rel + row;
        int hh = ng / DHEAD, dd = ng - hh * DHEAD;
        *(float4*)(outB2 + ((size_t)hh * DPAD + dd) * L_TOK + m0 + ch * 8) =
            *(const float4*)(&Ls[row * 136 + ch * 8]);
      }
    }
  } else {
#pragma unroll
    for (int j = 0; j < 2; j++) {
      int ng = n0 + wn + j * 16 + l16;
      float bv = bias[ng];
#pragma unroll
      for (int i = 0; i < 4; i++) {
        int mb = m0 + wm + i * 16 + quad * 4;
#pragma unroll
        for (int r = 0; r < 4; r++) {
          size_t idx = (size_t)(mb + r) * D_DIM + ng;
          float v = acc[i][j][r] + bv + __bfloat162float(resid[idx]);
          outB[idx] = __float2bfloat16(v);
        }
      }
    }
  }
}

// ---------------------------------------------------------------------------
// final conv GEMM + SiLU: BM=64, BN=32, grid (64,4)=256 WGs.
// ---------------------------------------------------------------------------
__global__ __launch_bounds__(256) void final_small(const __hip_bfloat16* __restrict__ A,
                                                   const __hip_bfloat16* __restrict__ Bt,
                                                   float* __restrict__ out) {
  __shared__ __align__(16) __hip_bfloat16 As[64 * 72];
  __shared__ __align__(16) __hip_bfloat16 Bs[32 * 72];
  const int t = threadIdx.x;
  const int wave = t >> 6, lane = t & 63, quad = lane >> 4, l16 = lane & 15;
  const int wm = (wave & 2) * 16;   // 0 or 32
  const int wn = (wave & 1) * 16;   // 0 or 16
  const int m0 = blockIdx.x * 64, n0 = blockIdx.y * 32;

  float4v acc[2];
  acc[0] = (float4v){0.f, 0.f, 0.f, 0.f};
  acc[1] = (float4v){0.f, 0.f, 0.f, 0.f};

  const int arow = t >> 3, ach = t & 7;
  for (int k0 = 0; k0 < D_DIM; k0 += 64) {
    __syncthreads();
#pragma unroll
    for (int u = 0; u < 2; u++) {
      int row = u * 32 + arow;
      *(float4*)(&As[row * 72 + ach * 8]) =
          *(const float4*)(A + (size_t)(m0 + row) * D_DIM + k0 + ach * 8);
    }
    if (arow < 32)
      *(float4*)(&Bs[arow * 72 + ach * 8]) =
          *(const float4*)(Bt + (size_t)(n0 + arow) * D_DIM + k0 + ach * 8);
    __syncthreads();
    short8 af[2][2], bfr[2];
#pragma unroll
    for (int i = 0; i < 2; i++)
#pragma unroll
      for (int s = 0; s < 2; s++)
        af[i][s] = *(const short8*)(&As[(wm + i * 16 + l16) * 72 + s * 32 + quad * 8]);
#pragma unroll
    for (int s = 0; s < 2; s++)
      bfr[s] = *(const short8*)(&Bs[(wn + l16) * 72 + s * 32 + quad * 8]);
#pragma unroll
    for (int i = 0; i < 2; i++) {
      acc[i] = __builtin_amdgcn_mfma_f32_16x16x32_bf16(af[i][0], bfr[0], acc[i], 0, 0, 0);
      acc[i] = __builtin_amdgcn_mfma_f32_16x16x32_bf16(af[i][1], bfr[1], acc[i], 0, 0, 0);
    }
  }
  const int oc = n0 + wn + l16;
#pragma unroll
  for (int i = 0; i < 2; i++) {
    int mb = m0 + wm + i * 16 + quad * 4;
#pragma unroll
    for (int r = 0; r < 4; r++) {
      float v = acc[i][r];
      float sg = 1.f / (1.f + __expf(-v));
      out[(size_t)oc * L_TOK + mb + r] = v * sg;
    }
  }
}

// ---------------------------------------------------------------------------
// bf16 MFMA flash attention — R7 structure + fixes:
//  * V staged only d<72 (VbT pad rows are never written -> don't read them);
//    Vt rows 72..79 zeroed once (PV nt=4 frag touches them).
//  * exp2 arg fused: p = exp2(fma(S, scale2, -mnew)) (S kept raw).
//  * alpha-ballot: skip Of rescale + shuffles when all alpha == 1 (exact).
// ---------------------------------------------------------------------------
#define KS_STRIDE 104
#define VT_STRIDE 72
#define PS_STRIDE 72

__global__ __launch_bounds__(256, 2) void attn_mfma(const __hip_bfloat16* __restrict__ Qb,
                                                    const __hip_bfloat16* __restrict__ Kb,
                                                    const __hip_bfloat16* __restrict__ VbT,
                                                    __hip_bfloat16* __restrict__ Opart,
                                                    float* __restrict__ Ml) {
  __shared__ __align__(16) __hip_bfloat16 Ks[64 * KS_STRIDE];      // 13312 B
  __shared__ __align__(16) __hip_bfloat16 Vt[80 * VT_STRIDE];      // 11520 B
  __shared__ __align__(16) __hip_bfloat16 Ps[4 * 64 * PS_STRIDE];  // 36864 B

  const int bid = blockIdx.x;
  const int h = bid & 7;                  // head -> XCD affinity
  const int rest = bid >> 3;
  const int ksp = rest & 3;
  const int qblk = rest >> 2;             // 0..15
  const int t = threadIdx.x;
  const int wave = t >> 6;
  const int lane = t & 63;
  const int quad = lane >> 4;
  const int l16 = lane & 15;

  const __hip_bfloat16* Qh = Qb + (size_t)h * L_TOK * DPAD;
  const __hip_bfloat16* Kh = Kb + (size_t)h * L_TOK * DPAD;
  const __hip_bfloat16* VhT = VbT + (size_t)h * DPAD * L_TOK;

  // Q as MFMA B operand: lane holds Q[q=l16][d=s*32+quad*8+j]; d>=72 pad -> 0
  const int qbase = qblk * 256 + wave * 64;
  short8 qf[4][3];
#pragma unroll
  for (int mi = 0; mi < 4; mi++) {
#pragma unroll
    for (int s = 0; s < 3; s++) {
      if (s == 2 && quad >= 1) {
        qf[mi][s] = (short8){0, 0, 0, 0, 0, 0, 0, 0};
      } else {
        qf[mi][s] = *(const short8*)(Qh + (size_t)(qbase + mi * 16 + l16) * DPAD + s * 32 + quad * 8);
      }
    }
  }

  // one-time zero of pads: Ks cols 72..95 and Vt rows 72..79 (stale-LDS guard)
  const float4 zero4 = {0.f, 0.f, 0.f, 0.f};
  if (t < 192) {
    int row = t / 3, ch = 9 + t % 3;
    *(float4*)(&Ks[row * KS_STRIDE + ch * 8]) = zero4;
  }
  if (t >= 192) {   // 64 threads: 8 rows x 8 chunks = rows 72..79, cols 0..63
    int e = t - 192;
    int d = 72 + (e >> 3), ch = e & 7;
    *(float4*)(&Vt[d * VT_STRIDE + ch * 8]) = zero4;
  }

  float4v Of[4][5];
#pragma unroll
  for (int mi = 0; mi < 4; mi++)
#pragma unroll
    for (int nt = 0; nt < 5; nt++) Of[mi][nt] = (float4v){0.f, 0.f, 0.f, 0.f};
  float mrow[4] = {-INFINITY, -INFINITY, -INFINITY, -INFINITY};  // log2 domain
  float lrow[4] = {0.f, 0.f, 0.f, 0.f};
  const float scale2 = 0.11785113019775792f * LOG2E;  // 72^-0.5 * log2(e)

  __hip_bfloat16* myPs = Ps + wave * 64 * PS_STRIDE;
  const int kstart = ksp * 1024;            // 16 tiles * 64 keys

  for (int kt = 0; kt < 16; kt++) {
    const int kbase = kstart + kt * 64;
    __syncthreads();  // prior tile's K/V reads complete

    // stage K tile [64 keys][d<72] : 576 chunks
    for (int e = t; e < 576; e += 256) {
      int row = e / 9, ch = e - row * 9;
      *(float4*)(&Ks[row * KS_STRIDE + ch * 8]) =
          *(const float4*)(Kh + (size_t)(kbase + row) * DPAD + ch * 8);
    }
    // stage V^T tile [72 d][64 keys] : 576 chunks (pad rows pre-zeroed)
    for (int e = t; e < 576; e += 256) {
      int d = e >> 3, ch = e & 7;
      *(float4*)(&Vt[d * VT_STRIDE + ch * 8]) =
          *(const float4*)(VhT + (size_t)d * L_TOK + kbase + ch * 8);
    }
    __syncthreads();

    // S^T = K Q^T (raw scores): A = K-frag shared across 4 q-frags
    float4v S[4][4];
#pragma unroll
    for (int ks = 0; ks < 4; ks++) {
      float4v a0 = (float4v){0.f, 0.f, 0.f, 0.f};
      float4v a1 = a0, a2 = a0, a3 = a0;
#pragma unroll
      for (int s = 0; s < 3; s++) {
        short8 kf = *(const short8*)(&Ks[(ks * 16 + l16) * KS_STRIDE + s * 32 + quad * 8]);
        a0 = __builtin_amdgcn_mfma_f32_16x16x32_bf16(kf, qf[0][s], a0, 0, 0, 0);
        a1 = __builtin_amdgcn_mfma_f32_16x16x32_bf16(kf, qf[1][s], a1, 0, 0, 0);
        a2 = __builtin_amdgcn_mfma_f32_16x16x32_bf16(kf, qf[2][s], a2, 0, 0, 0);
        a3 = __builtin_amdgcn_mfma_f32_16x16x32_bf16(kf, qf[3][s], a3, 0, 0, 0);
      }
#pragma unroll
      for (int r = 0; r < 4; r++) {
        S[0][ks][r] = a0[r]; S[1][ks][r] = a1[r];
        S[2][ks][r] = a2[r]; S[3][ks][r] = a3[r];
      }
    }

    // softmax (log2 domain, scale fused into exp2 arg via fma)
    float alpha[4];
#pragma unroll
    for (int mi = 0; mi < 4; mi++) {
      float tm = -INFINITY;
#pragma unroll
      for (int ks = 0; ks < 4; ks++)
#pragma unroll
        for (int r = 0; r < 4; r++) tm = fmaxf(tm, S[mi][ks][r]);
      tm = fmaxf(tm, __shfl_xor(tm, 16));
      tm = fmaxf(tm, __shfl_xor(tm, 32));
      float mnew = fmaxf(mrow[mi], tm * scale2);
      alpha[mi] = exp2f(mrow[mi] - mnew);
      mrow[mi] = mnew;
      float ps = 0.f;
#pragma unroll
      for (int ks = 0; ks < 4; ks++)
#pragma unroll
        for (int r = 0; r < 4; r++) {
          float p = exp2f(fmaf(S[mi][ks][r], scale2, -mnew));
          ps += p;
          S[mi][ks][r] = p;
        }
      ps += __shfl_xor(ps, 16);
      ps += __shfl_xor(ps, 32);
      lrow[mi] = lrow[mi] * alpha[mi] + ps;
    }

    // P writes: Ps[q][key], 4 consecutive keys packed per ds_write_b64
#pragma unroll
    for (int mi = 0; mi < 4; mi++) {
#pragma unroll
      for (int ks = 0; ks < 4; ks++) {
        union { short4v v; __hip_bfloat16 hh[4]; } pk;
#pragma unroll
        for (int r = 0; r < 4; r++) pk.hh[r] = __float2bfloat16(S[mi][ks][r]);
        *(short4v*)(&myPs[(mi * 16 + l16) * PS_STRIDE + ks * 16 + quad * 4]) = pk.v;
      }
    }

    // Of rescale only when some alpha != 1 (max actually moved) — exact skip
    bool need = (alpha[0] != 1.f) | (alpha[1] != 1.f) | (alpha[2] != 1.f) | (alpha[3] != 1.f);
    if (__ballot(need) != 0ull) {
      float aq[4][4];
#pragma unroll
      for (int mi = 0; mi < 4; mi++)
#pragma unroll
        for (int r = 0; r < 4; r++) aq[mi][r] = __shfl(alpha[mi], quad * 4 + r);
#pragma unroll
      for (int mi = 0; mi < 4; mi++)
#pragma unroll
        for (int nt = 0; nt < 5; nt++)
#pragma unroll
          for (int r = 0; r < 4; r++) Of[mi][nt][r] *= aq[mi][r];
    }

    // O += P V : A = P (per-wave LDS, same-wave in-order), B = V-frag
#pragma unroll
    for (int kstep = 0; kstep < 2; kstep++) {
      short8 pa[4];
#pragma unroll
      for (int mi = 0; mi < 4; mi++)
        pa[mi] = *(const short8*)(&myPs[(mi * 16 + l16) * PS_STRIDE + kstep * 32 + quad * 8]);
#pragma unroll
      for (int nt = 0; nt < 5; nt++) {
        short8 vb = *(const short8*)(&Vt[(nt * 16 + l16) * VT_STRIDE + kstep * 32 + quad * 8]);
        Of[0][nt] = __builtin_amdgcn_mfma_f32_16x16x32_bf16(pa[0], vb, Of[0][nt], 0, 0, 0);
        Of[1][nt] = __builtin_amdgcn_mfma_f32_16x16x32_bf16(pa[1], vb, Of[1][nt], 0, 0, 0);
        Of[2][nt] = __builtin_amdgcn_mfma_f32_16x16x32_bf16(pa[2], vb, Of[2][nt], 0, 0, 0);
        Of[3][nt] = __builtin_amdgcn_mfma_f32_16x16x32_bf16(pa[3], vb, Of[3][nt], 0, 0, 0);
      }
    }
  }

  // store unnormalized partials (72 cols) + m,l
  const size_t pb = ((size_t)ksp * NHEADS + h) * L_TOK;
#pragma unroll
  for (int mi = 0; mi < 4; mi++) {
#pragma unroll
    for (int nt = 0; nt < 5; nt++) {
      int d = nt * 16 + l16;
      if (d < DHEAD) {
#pragma unroll
        for (int r = 0; r < 4; r++) {
          int q = qbase + mi * 16 + quad * 4 + r;
          Opart[(pb + q) * 72 + d] = __float2bfloat16(Of[mi][nt][r]);
        }
      }
    }
  }
  if (quad == 0) {   // lanes 0..15 hold stats for q = qbase + mi*16 + l16
#pragma unroll
    for (int mi = 0; mi < 4; mi++) {
      int q = qbase + mi * 16 + l16;
      Ml[(pb + q) * 2] = mrow[mi];
      Ml[(pb + q) * 2 + 1] = lrow[mi];
    }
  }
}

// ---------------------------------------------------------------------------
// flash-merge of the KSPLIT partials (log2-domain m) -> ob[q][h*72+d] bf16
// ---------------------------------------------------------------------------
__global__ __launch_bounds__(256) void attn_merge(const __hip_bfloat16* __restrict__ Opart,
                                                  const float* __restrict__ Ml,
                                                  __hip_bfloat16* __restrict__ ob) {
  int idx = blockIdx.x * 256 + threadIdx.x;     // 8h * 4096q * 9ch
  int h = idx / (L_TOK * 9);
  int rem = idx - h * (L_TOK * 9);
  int q = rem / 9;
  int ch = rem - q * 9;
  size_t b[KSPLIT];
  float m[KSPLIT], l[KSPLIT];
  float mx = -INFINITY;
#pragma unroll
  for (int s = 0; s < KSPLIT; s++) {
    b[s] = ((size_t)s * NHEADS + h) * L_TOK + q;
    m[s] = Ml[b[s] * 2];
    l[s] = Ml[b[s] * 2 + 1];
    mx = fmaxf(mx, m[s]);
  }
  float w[KSPLIT], denom = 0.f;
#pragma unroll
  for (int s = 0; s < KSPLIT; s++) {
    w[s] = exp2f(m[s] - mx);
    denom += w[s] * l[s];
  }
  float inv = 1.f / denom;
  float acc[8] = {0, 0, 0, 0, 0, 0, 0, 0};
#pragma unroll
  for (int s = 0; s < KSPLIT; s++) {
    short8 o = *(const short8*)(Opart + b[s] * 72 + ch * 8);
#pragma unroll
    for (int j = 0; j < 8; j++) {
      union { short ss; __hip_bfloat16 bb; } u;
      u.ss = o[j];
      acc[j] += w[s] * __bfloat162float(u.bb);
    }
  }
  __hip_bfloat16* dst = ob + (size_t)q * D_DIM + h * DHEAD + ch * 8;
#pragma unroll
  for (int j = 0; j < 8; j++) dst[j] = __float2bfloat16(acc[j] * inv);
}

// ---------------------------------------------------------------------------
extern "C" void kernel_launch(void* const* d_in, const int* in_sizes, int n_in,
                              void* d_out, int out_size, void* d_ws, size_t ws_size,
                              hipStream_t stream) {
  const float* fea    = (const float*)d_in[0];
  const float* w_qkv  = (const float*)d_in[1];
  const float* b_qkv  = (const float*)d_in[2];
  const float* w_out  = (const float*)d_in[3];
  const float* b_out  = (const float*)d_in[4];
  const float* conv_w = (const float*)d_in[5];
  float* out = (float*)d_out;

  __hip_bfloat16* xb    = (__hip_bfloat16*)d_ws;             // 4096*576
  __hip_bfloat16* WqkvT = xb + (size_t)L_TOK * D_DIM;        // 1728*576
  __hip_bfloat16* WoT   = WqkvT + (size_t)1728 * D_DIM;      // 576*576
  __hip_bfloat16* CwB   = WoT + (size_t)D_DIM * D_DIM;       // 128*576
  __hip_bfloat16* QKb   = CwB + (size_t)128 * D_DIM;         // 2*HSZ (Q,K)
  __hip_bfloat16* VbT   = QKb + 2 * HSZ;                     // HSZ (V^T)
  __hip_bfloat16* Opart = VbT + HSZ;                         // KSPLIT*8*4096*72
  float* Ml = (float*)(Opart + (size_t)KSPLIT * NHEADS * L_TOK * 72);
  // ob aliases QKb (Q,K dead after attn); xr aliases Opart (dead after merge)
  __hip_bfloat16* ob = QKb;
  __hip_bfloat16* xr = Opart;

  prep_all<<<1124, 256, 0, stream>>>(fea, w_qkv, w_out, conv_w, xb, WqkvT, WoT, CwB);
  gemm_mfma<0><<<dim3(32, 27), 256, 0, stream>>>(xb, WqkvT, b_qkv, nullptr, QKb, VbT);
  attn_mfma<<<512, 256, 0, stream>>>(QKb, QKb + HSZ, VbT, Opart, Ml);
  attn_merge<<<1152, 256, 0, stream>>>(Opart, Ml, ob);
  gemm_mfma<1><<<dim3(32, 9), 256, 0, stream>>>(ob, WoT, b_out, xb, xr, nullptr);
  final_small<<<dim3(64, 4), 256, 0, stream>>>(xr, CwB, out);
}

// Round 11
// 218.303 us; speedup vs baseline: 1.1780x; 1.0219x over previous
//
#include <hip/hip_runtime.h>
#include <hip/hip_bf16.h>
#include <math.h>

#define L_TOK 4096
#define D_DIM 576
#define NHEADS 8
#define DHEAD 72
#define DPAD 96
#define HSZ ((size_t)NHEADS * L_TOK * DPAD)   // elems per head-padded tensor
#define KSPLIT 4
#define LOG2E 1.4426950408889634f

typedef __attribute__((ext_vector_type(8))) short short8;
typedef __attribute__((ext_vector_type(4))) short short4v;
typedef __attribute__((ext_vector_type(4))) float float4v;

union F4S8 {
  float4 f4;
  short8 s8;
  __hip_bfloat16 h[8];
};

// ---------------------------------------------------------------------------
// fused pre-pass: unfold (512 blocks) + w_qkv^T (243) + w_out^T (81) +
// conv_w cvt (288) = 1124 blocks, one launch.
// ---------------------------------------------------------------------------
__device__ inline void tc_body(const float* __restrict__ src,
                               __hip_bfloat16* __restrict__ dst, int R, int C,
                               int bi, int bj, int t, __hip_bfloat16* Ts) {
  const int col = t & 63, row4 = t >> 6;
#pragma unroll
  for (int u = 0; u < 16; u++) {
    int r = u * 4 + row4;
    Ts[r * 68 + col] = __float2bfloat16(src[(size_t)(bj * 64 + r) * C + bi * 64 + col]);
  }
  __syncthreads();
#pragma unroll
  for (int u = 0; u < 16; u++) {
    int c = u * 4 + row4;
    dst[(size_t)(bi * 64 + c) * R + bj * 64 + col] = Ts[col * 68 + c];
  }
}

__global__ __launch_bounds__(256) void prep_all(const float* __restrict__ fea,
                                                const float* __restrict__ w_qkv,
                                                const float* __restrict__ w_out,
                                                const float* __restrict__ conv_w,
                                                __hip_bfloat16* __restrict__ xb,
                                                __hip_bfloat16* __restrict__ WqkvT,
                                                __hip_bfloat16* __restrict__ WoT,
                                                __hip_bfloat16* __restrict__ CwB) {
  __shared__ float Shm[3120];        // 12480 B; reused as Ts (8704 B)
  const int b = blockIdx.x;
  const int t = threadIdx.x;
  if (b < 512) {
    // unfold 3x3 s2 p1 -> xb [4096][576], LDS-tiled (coalesced both sides)
    float* Lf = Shm;                 // [24][130]
    const int ho = b & 63;
    const int c0 = (b >> 6) * 8;
    for (int e = t; e < 3072; e += 256) {
      int c = e / 384;
      int rr = (e / 128) % 3;
      int w = e & 127;
      int h = 2 * ho + rr - 1;
      float v = 0.f;
      if ((unsigned)h < 128u) v = fea[(size_t)(c0 + c) * 16384 + h * 128 + w];
      Lf[(c * 3 + rr) * 130 + w + 1] = v;
    }
    if (t < 24) { Lf[t * 130] = 0.f; Lf[t * 130 + 129] = 0.f; }
    __syncthreads();
    for (int e = t; e < 576; e += 256) {
      int wo = e / 9, ch = e - wo * 9;
      F4S8 u;
#pragma unroll
      for (int j = 0; j < 8; j++) {
        int dd = ch * 8 + j;
        int c = dd / 9, k = dd - c * 9;
        int ki = k / 3, kj = k - ki * 3;
        u.h[j] = __float2bfloat16(Lf[(c * 3 + ki) * 130 + 2 * wo + kj]);
      }
      *(float4*)(xb + (size_t)(ho * 64 + wo) * D_DIM + c0 * 9 + ch * 8) = u.f4;
    }
  } else if (b < 755) {
    int bb = b - 512;
    tc_body(w_qkv, WqkvT, D_DIM, 1728, bb % 27, bb / 27, t, (__hip_bfloat16*)Shm);
  } else if (b < 836) {
    int bb = b - 755;
    tc_body(w_out, WoT, D_DIM, D_DIM, bb % 9, bb / 9, t, (__hip_bfloat16*)Shm);
  } else {
    int i = (b - 836) * 256 + t;
    CwB[i] = __float2bfloat16(conv_w[i]);
  }
}

// ---------------------------------------------------------------------------
// bf16 MFMA GEMM: C[M][N] = A[M][576] @ Bt[N][576]^T (+epilogue)
// BM=128, BN=64, BK=64; 4 waves 2x2.
// EPI 0: QKV. Q,K -> [h][L][96] coalesced; V -> V^T [h][96][L] via LDS
//        transpose tile ALIASED onto As (dead after K-loop; branch is
//        WG-uniform so the barrier is legal). LDS 27.6 KB -> 4 WG/CU.
// EPI 1: oproj (+bias +residual -> bf16)
// ---------------------------------------------------------------------------
template <int EPI>
__global__ __launch_bounds__(256) void gemm_mfma(const __hip_bfloat16* __restrict__ A,
                                                 const __hip_bfloat16* __restrict__ Bt,
                                                 const float* __restrict__ bias,
                                                 const __hip_bfloat16* __restrict__ resid,
                                                 __hip_bfloat16* __restrict__ outB,
                                                 __hip_bfloat16* __restrict__ outB2) {
  constexpr int K = D_DIM;
  __shared__ __align__(16) __hip_bfloat16 As[128 * 72];   // 18432 B
  __shared__ __align__(16) __hip_bfloat16 Bs[64 * 72];    // 9216 B
  const int t = threadIdx.x;
  const int wave = t >> 6, lane = t & 63, quad = lane >> 4, l16 = lane & 15;
  const int wm = (wave & 2) * 32;   // 0 or 64
  const int wn = (wave & 1) * 32;   // 0 or 32
  const int m0 = blockIdx.x * 128, n0 = blockIdx.y * 64;

  float4v acc[4][2];
#pragma unroll
  for (int i = 0; i < 4; i++)
#pragma unroll
    for (int j = 0; j < 2; j++) acc[i][j] = (float4v){0.f, 0.f, 0.f, 0.f};

  const int arow = t >> 3, ach = t & 7;
  for (int k0 = 0; k0 < K; k0 += 64) {
    __syncthreads();
#pragma unroll
    for (int u = 0; u < 4; u++) {
      int row = u * 32 + arow;
      *(float4*)(&As[row * 72 + ach * 8]) =
          *(const float4*)(A + (size_t)(m0 + row) * K + k0 + ach * 8);
    }
#pragma unroll
    for (int u = 0; u < 2; u++) {
      int row = u * 32 + arow;
      *(float4*)(&Bs[row * 72 + ach * 8]) =
          *(const float4*)(Bt + (size_t)(n0 + row) * K + k0 + ach * 8);
    }
    __syncthreads();
    short8 af[4][2], bfr[2][2];
#pragma unroll
    for (int i = 0; i < 4; i++)
#pragma unroll
      for (int s = 0; s < 2; s++)
        af[i][s] = *(const short8*)(&As[(wm + i * 16 + l16) * 72 + s * 32 + quad * 8]);
#pragma unroll
    for (int j = 0; j < 2; j++)
#pragma unroll
      for (int s = 0; s < 2; s++)
        bfr[j][s] = *(const short8*)(&Bs[(wn + j * 16 + l16) * 72 + s * 32 + quad * 8]);
#pragma unroll
    for (int i = 0; i < 4; i++)
#pragma unroll
      for (int j = 0; j < 2; j++) {
        acc[i][j] = __builtin_amdgcn_mfma_f32_16x16x32_bf16(af[i][0], bfr[j][0], acc[i][j], 0, 0, 0);
        acc[i][j] = __builtin_amdgcn_mfma_f32_16x16x32_bf16(af[i][1], bfr[j][1], acc[i][j], 0, 0, 0);
      }
  }

  // epilogue; C/D layout: col = l16 (n), row = quad*4 + r (m)
  if (EPI == 0) {
    const int part = n0 / D_DIM;          // tile lies in exactly one of Q/K/V
    if (part < 2) {
      __hip_bfloat16* dst = outB + (size_t)part * HSZ;
#pragma unroll
      for (int j = 0; j < 2; j++) {
        int ng = n0 + wn + j * 16 + l16;
        float bv = bias[ng];
        int rem = ng - part * D_DIM;
        int h = rem / DHEAD;
        int d = rem - h * DHEAD;
#pragma unroll
        for (int i = 0; i < 4; i++) {
          int mb = m0 + wm + i * 16 + quad * 4;
#pragma unroll
          for (int r = 0; r < 4; r++)
            dst[((size_t)h * L_TOK + mb + r) * DPAD + d] = __float2bfloat16(acc[i][j][r] + bv);
        }
      }
    } else {
      // V: transpose via LDS (Ls aliases As: 17408 B <= 18432 B), float4 stores
      __hip_bfloat16* Ls = As;
      __syncthreads();   // WG-uniform branch; wait all waves' As frag reads
      const int n0rel = n0 - 2 * D_DIM;
#pragma unroll
      for (int j = 0; j < 2; j++) {
        int nloc = wn + j * 16 + l16;
        float bv = bias[n0 + nloc];
#pragma unroll
        for (int i = 0; i < 4; i++) {
          int mloc = wm + i * 16 + quad * 4;
#pragma unroll
          for (int r = 0; r < 4; r++)
            Ls[nloc * 136 + mloc + r] = __float2bfloat16(acc[i][j][r] + bv);
        }
      }
      __syncthreads();
      for (int e = t; e < 1024; e += 256) {
        int row = e >> 4, ch = e & 15;
        int ng = n0rel + row;
        int hh = ng / DHEAD, dd = ng - hh * DHEAD;
        *(float4*)(outB2 + ((size_t)hh * DPAD + dd) * L_TOK + m0 + ch * 8) =
            *(const float4*)(&Ls[row * 136 + ch * 8]);
      }
    }
  } else {
#pragma unroll
    for (int j = 0; j < 2; j++) {
      int ng = n0 + wn + j * 16 + l16;
      float bv = bias[ng];
#pragma unroll
      for (int i = 0; i < 4; i++) {
        int mb = m0 + wm + i * 16 + quad * 4;
#pragma unroll
        for (int r = 0; r < 4; r++) {
          size_t idx = (size_t)(mb + r) * D_DIM + ng;
          float v = acc[i][j][r] + bv + __bfloat162float(resid[idx]);
          outB[idx] = __float2bfloat16(v);
        }
      }
    }
  }
}

// ---------------------------------------------------------------------------
// final conv GEMM + SiLU: BM=32, BN=32, grid (128,4)=512 WGs (2/CU so the
// 9 staging barriers have a co-resident WG to hide behind).
// ---------------------------------------------------------------------------
__global__ __launch_bounds__(256) void final_small(const __hip_bfloat16* __restrict__ A,
                                                   const __hip_bfloat16* __restrict__ Bt,
                                                   float* __restrict__ out) {
  __shared__ __align__(16) __hip_bfloat16 As[32 * 72];
  __shared__ __align__(16) __hip_bfloat16 Bs[32 * 72];
  const int t = threadIdx.x;
  const int wave = t >> 6, lane = t & 63, quad = lane >> 4, l16 = lane & 15;
  const int wm = (wave & 2) * 8;    // 0 or 16
  const int wn = (wave & 1) * 16;   // 0 or 16
  const int m0 = blockIdx.x * 32, n0 = blockIdx.y * 32;

  float4v acc = (float4v){0.f, 0.f, 0.f, 0.f};

  const int arow = t >> 3, ach = t & 7;   // 32 rows x 8 chunks = 256
  for (int k0 = 0; k0 < D_DIM; k0 += 64) {
    __syncthreads();
    *(float4*)(&As[arow * 72 + ach * 8]) =
        *(const float4*)(A + (size_t)(m0 + arow) * D_DIM + k0 + ach * 8);
    *(float4*)(&Bs[arow * 72 + ach * 8]) =
        *(const float4*)(Bt + (size_t)(n0 + arow) * D_DIM + k0 + ach * 8);
    __syncthreads();
    short8 af[2], bfr[2];
#pragma unroll
    for (int s = 0; s < 2; s++) {
      af[s] = *(const short8*)(&As[(wm + l16) * 72 + s * 32 + quad * 8]);
      bfr[s] = *(const short8*)(&Bs[(wn + l16) * 72 + s * 32 + quad * 8]);
    }
    acc = __builtin_amdgcn_mfma_f32_16x16x32_bf16(af[0], bfr[0], acc, 0, 0, 0);
    acc = __builtin_amdgcn_mfma_f32_16x16x32_bf16(af[1], bfr[1], acc, 0, 0, 0);
  }
  const int oc = n0 + wn + l16;
  const int mb = m0 + wm + quad * 4;
#pragma unroll
  for (int r = 0; r < 4; r++) {
    float v = acc[r];
    float sg = 1.f / (1.f + __expf(-v));
    out[(size_t)oc * L_TOK + mb + r] = v * sg;
  }
}

// ---------------------------------------------------------------------------
// bf16 MFMA flash attention — R10 structure + global->reg->LDS pipeline:
// tile k+1's K/V loads issue into registers right after tile k's staging
// barrier; next iteration's LDS store hits resident registers (no global
// latency inside the barrier-to-barrier critical path). Per-thread staging
// split is wave-uniform (3rd chunk = wave 0 only).
// ---------------------------------------------------------------------------
#define KS_STRIDE 104
#define VT_STRIDE 72
#define PS_STRIDE 72

__global__ __launch_bounds__(256, 2) void attn_mfma(const __hip_bfloat16* __restrict__ Qb,
                                                    const __hip_bfloat16* __restrict__ Kb,
                                                    const __hip_bfloat16* __restrict__ VbT,
                                                    __hip_bfloat16* __restrict__ Opart,
                                                    float* __restrict__ Ml) {
  __shared__ __align__(16) __hip_bfloat16 Ks[64 * KS_STRIDE];      // 13312 B
  __shared__ __align__(16) __hip_bfloat16 Vt[80 * VT_STRIDE];      // 11520 B
  __shared__ __align__(16) __hip_bfloat16 Ps[4 * 64 * PS_STRIDE];  // 36864 B

  const int bid = blockIdx.x;
  const int h = bid & 7;                  // head -> XCD affinity
  const int rest = bid >> 3;
  const int ksp = rest & 3;
  const int qblk = rest >> 2;             // 0..15
  const int t = threadIdx.x;
  const int wave = t >> 6;
  const int lane = t & 63;
  const int quad = lane >> 4;
  const int l16 = lane & 15;

  const __hip_bfloat16* Qh = Qb + (size_t)h * L_TOK * DPAD;
  const __hip_bfloat16* Kh = Kb + (size_t)h * L_TOK * DPAD;
  const __hip_bfloat16* VhT = VbT + (size_t)h * DPAD * L_TOK;

  // Q as MFMA B operand: lane holds Q[q=l16][d=s*32+quad*8+j]; d>=72 pad -> 0
  const int qbase = qblk * 256 + wave * 64;
  short8 qf[4][3];
#pragma unroll
  for (int mi = 0; mi < 4; mi++) {
#pragma unroll
    for (int s = 0; s < 3; s++) {
      if (s == 2 && quad >= 1) {
        qf[mi][s] = (short8){0, 0, 0, 0, 0, 0, 0, 0};
      } else {
        qf[mi][s] = *(const short8*)(Qh + (size_t)(qbase + mi * 16 + l16) * DPAD + s * 32 + quad * 8);
      }
    }
  }

  // one-time zero of pads: Ks cols 72..95 and Vt rows 72..79 (stale-LDS guard)
  const float4 zero4 = {0.f, 0.f, 0.f, 0.f};
  if (t < 192) {
    int row = t / 3, ch = 9 + t % 3;
    *(float4*)(&Ks[row * KS_STRIDE + ch * 8]) = zero4;
  }
  if (t >= 192) {   // 64 threads: rows 72..79 x 8 chunks
    int e = t - 192;
    int d = 72 + (e >> 3), ch = e & 7;
    *(float4*)(&Vt[d * VT_STRIDE + ch * 8]) = zero4;
  }

  // per-thread staging geometry (loop-invariant); 576 chunks each for K and V
  const int rK0 = t / 9, cK0 = t % 9;
  const int rK1 = (t + 256) / 9, cK1 = (t + 256) % 9;
  const int rK2 = (t + 512) / 9, cK2 = (t + 512) % 9;   // wave 0 only
  const int dV0 = t >> 3, cV0 = t & 7;                  // dV1=dV0+32, dV2=dV0+64
  float4 kp0, kp1, kp2, vp0, vp1, vp2;
  const int kstart = ksp * 1024;            // 16 tiles * 64 keys

  auto prefetch = [&](int kbase) {
    kp0 = *(const float4*)(Kh + (size_t)(kbase + rK0) * DPAD + cK0 * 8);
    kp1 = *(const float4*)(Kh + (size_t)(kbase + rK1) * DPAD + cK1 * 8);
    vp0 = *(const float4*)(VhT + (size_t)dV0 * L_TOK + kbase + cV0 * 8);
    vp1 = *(const float4*)(VhT + (size_t)(dV0 + 32) * L_TOK + kbase + cV0 * 8);
    if (wave == 0) {
      kp2 = *(const float4*)(Kh + (size_t)(kbase + rK2) * DPAD + cK2 * 8);
      vp2 = *(const float4*)(VhT + (size_t)(dV0 + 64) * L_TOK + kbase + cV0 * 8);
    }
  };
  prefetch(kstart);

  float4v Of[4][5];
#pragma unroll
  for (int mi = 0; mi < 4; mi++)
#pragma unroll
    for (int nt = 0; nt < 5; nt++) Of[mi][nt] = (float4v){0.f, 0.f, 0.f, 0.f};
  float mrow[4] = {-INFINITY, -INFINITY, -INFINITY, -INFINITY};  // log2 domain
  float lrow[4] = {0.f, 0.f, 0.f, 0.f};
  const float scale2 = 0.11785113019775792f * LOG2E;  // 72^-0.5 * log2(e)

  __hip_bfloat16* myPs = Ps + wave * 64 * PS_STRIDE;

  for (int kt = 0; kt < 16; kt++) {
    __syncthreads();  // prior tile's K/V LDS reads complete

    // store prefetched registers -> LDS (no global latency here)
    *(float4*)(&Ks[rK0 * KS_STRIDE + cK0 * 8]) = kp0;
    *(float4*)(&Ks[rK1 * KS_STRIDE + cK1 * 8]) = kp1;
    *(float4*)(&Vt[dV0 * VT_STRIDE + cV0 * 8]) = vp0;
    *(float4*)(&Vt[(dV0 + 32) * VT_STRIDE + cV0 * 8]) = vp1;
    if (wave == 0) {
      *(float4*)(&Ks[rK2 * KS_STRIDE + cK2 * 8]) = kp2;
      *(float4*)(&Vt[(dV0 + 64) * VT_STRIDE + cV0 * 8]) = vp2;
    }
    __syncthreads();  // staging visible

    // issue next tile's loads now; they complete during this tile's compute
    if (kt + 1 < 16) prefetch(kstart + (kt + 1) * 64);

    // S^T = K Q^T (raw scores): A = K-frag shared across 4 q-frags
    float4v S[4][4];
#pragma unroll
    for (int ks = 0; ks < 4; ks++) {
      float4v a0 = (float4v){0.f, 0.f, 0.f, 0.f};
      float4v a1 = a0, a2 = a0, a3 = a0;
#pragma unroll
      for (int s = 0; s < 3; s++) {
        short8 kf = *(const short8*)(&Ks[(ks * 16 + l16) * KS_STRIDE + s * 32 + quad * 8]);
        a0 = __builtin_amdgcn_mfma_f32_16x16x32_bf16(kf, qf[0][s], a0, 0, 0, 0);
        a1 = __builtin_amdgcn_mfma_f32_16x16x32_bf16(kf, qf[1][s], a1, 0, 0, 0);
        a2 = __builtin_amdgcn_mfma_f32_16x16x32_bf16(kf, qf[2][s], a2, 0, 0, 0);
        a3 = __builtin_amdgcn_mfma_f32_16x16x32_bf16(kf, qf[3][s], a3, 0, 0, 0);
      }
#pragma unroll
      for (int r = 0; r < 4; r++) {
        S[0][ks][r] = a0[r]; S[1][ks][r] = a1[r];
        S[2][ks][r] = a2[r]; S[3][ks][r] = a3[r];
      }
    }

    // softmax (log2 domain, scale fused into exp2 arg via fma)
    float alpha[4];
#pragma unroll
    for (int mi = 0; mi < 4; mi++) {
      float tm = -INFINITY;
#pragma unroll
      for (int ks = 0; ks < 4; ks++)
#pragma unroll
        for (int r = 0; r < 4; r++) tm = fmaxf(tm, S[mi][ks][r]);
      tm = fmaxf(tm, __shfl_xor(tm, 16));
      tm = fmaxf(tm, __shfl_xor(tm, 32));
      float mnew = fmaxf(mrow[mi], tm * scale2);
      alpha[mi] = exp2f(mrow[mi] - mnew);
      mrow[mi] = mnew;
      float ps = 0.f;
#pragma unroll
      for (int ks = 0; ks < 4; ks++)
#pragma unroll
        for (int r = 0; r < 4; r++) {
          float p = exp2f(fmaf(S[mi][ks][r], scale2, -mnew));
          ps += p;
          S[mi][ks][r] = p;
        }
      ps += __shfl_xor(ps, 16);
      ps += __shfl_xor(ps, 32);
      lrow[mi] = lrow[mi] * alpha[mi] + ps;
    }

    // P writes: Ps[q][key], 4 consecutive keys packed per ds_write_b64
#pragma unroll
    for (int mi = 0; mi < 4; mi++) {
#pragma unroll
      for (int ks = 0; ks < 4; ks++) {
        union { short4v v; __hip_bfloat16 hh[4]; } pk;
#pragma unroll
        for (int r = 0; r < 4; r++) pk.hh[r] = __float2bfloat16(S[mi][ks][r]);
        *(short4v*)(&myPs[(mi * 16 + l16) * PS_STRIDE + ks * 16 + quad * 4]) = pk.v;
      }
    }

    // Of rescale only when some alpha != 1 (max actually moved) — exact skip
    bool need = (alpha[0] != 1.f) | (alpha[1] != 1.f) | (alpha[2] != 1.f) | (alpha[3] != 1.f);
    if (__ballot(need) != 0ull) {
      float aq[4][4];
#pragma unroll
      for (int mi = 0; mi < 4; mi++)
#pragma unroll
        for (int r = 0; r < 4; r++) aq[mi][r] = __shfl(alpha[mi], quad * 4 + r);
#pragma unroll
      for (int mi = 0; mi < 4; mi++)
#pragma unroll
        for (int nt = 0; nt < 5; nt++)
#pragma unroll
          for (int r = 0; r < 4; r++) Of[mi][nt][r] *= aq[mi][r];
    }

    // O += P V : A = P (per-wave LDS, same-wave in-order), B = V-frag
#pragma unroll
    for (int kstep = 0; kstep < 2; kstep++) {
      short8 pa[4];
#pragma unroll
      for (int mi = 0; mi < 4; mi++)
        pa[mi] = *(const short8*)(&myPs[(mi * 16 + l16) * PS_STRIDE + kstep * 32 + quad * 8]);
#pragma unroll
      for (int nt = 0; nt < 5; nt++) {
        short8 vb = *(const short8*)(&Vt[(nt * 16 + l16) * VT_STRIDE + kstep * 32 + quad * 8]);
        Of[0][nt] = __builtin_amdgcn_mfma_f32_16x16x32_bf16(pa[0], vb, Of[0][nt], 0, 0, 0);
        Of[1][nt] = __builtin_amdgcn_mfma_f32_16x16x32_bf16(pa[1], vb, Of[1][nt], 0, 0, 0);
        Of[2][nt] = __builtin_amdgcn_mfma_f32_16x16x32_bf16(pa[2], vb, Of[2][nt], 0, 0, 0);
        Of[3][nt] = __builtin_amdgcn_mfma_f32_16x16x32_bf16(pa[3], vb, Of[3][nt], 0, 0, 0);
      }
    }
  }

  // store unnormalized partials (72 cols) + m,l
  const size_t pb = ((size_t)ksp * NHEADS + h) * L_TOK;
#pragma unroll
  for (int mi = 0; mi < 4; mi++) {
#pragma unroll
    for (int nt = 0; nt < 5; nt++) {
      int d = nt * 16 + l16;
      if (d < DHEAD) {
#pragma unroll
        for (int r = 0; r < 4; r++) {
          int q = qbase + mi * 16 + quad * 4 + r;
          Opart[(pb + q) * 72 + d] = __float2bfloat16(Of[mi][nt][r]);
        }
      }
    }
  }
  if (quad == 0) {   // lanes 0..15 hold stats for q = qbase + mi*16 + l16
#pragma unroll
    for (int mi = 0; mi < 4; mi++) {
      int q = qbase + mi * 16 + l16;
      Ml[(pb + q) * 2] = mrow[mi];
      Ml[(pb + q) * 2 + 1] = lrow[mi];
    }
  }
}

// ---------------------------------------------------------------------------
// flash-merge of the KSPLIT partials (log2-domain m) -> ob[q][h*72+d] bf16
// ---------------------------------------------------------------------------
__global__ __launch_bounds__(256) void attn_merge(const __hip_bfloat16* __restrict__ Opart,
                                                  const float* __restrict__ Ml,
                                                  __hip_bfloat16* __restrict__ ob) {
  int idx = blockIdx.x * 256 + threadIdx.x;     // 8h * 4096q * 9ch
  int h = idx / (L_TOK * 9);
  int rem = idx - h * (L_TOK * 9);
  int q = rem / 9;
  int ch = rem - q * 9;
  size_t b[KSPLIT];
  float m[KSPLIT], l[KSPLIT];
  float mx = -INFINITY;
#pragma unroll
  for (int s = 0; s < KSPLIT; s++) {
    b[s] = ((size_t)s * NHEADS + h) * L_TOK + q;
    m[s] = Ml[b[s] * 2];
    l[s] = Ml[b[s] * 2 + 1];
    mx = fmaxf(mx, m[s]);
  }
  float w[KSPLIT], denom = 0.f;
#pragma unroll
  for (int s = 0; s < KSPLIT; s++) {
    w[s] = exp2f(m[s] - mx);
    denom += w[s] * l[s];
  }
  float inv = 1.f / denom;
  float acc[8] = {0, 0, 0, 0, 0, 0, 0, 0};
#pragma unroll
  for (int s = 0; s < KSPLIT; s++) {
    short8 o = *(const short8*)(Opart + b[s] * 72 + ch * 8);
#pragma unroll
    for (int j = 0; j < 8; j++) {
      union { short ss; __hip_bfloat16 bb; } u;
      u.ss = o[j];
      acc[j] += w[s] * __bfloat162float(u.bb);
    }
  }
  __hip_bfloat16* dst = ob + (size_t)q * D_DIM + h * DHEAD + ch * 8;
#pragma unroll
  for (int j = 0; j < 8; j++) dst[j] = __float2bfloat16(acc[j] * inv);
}

// ---------------------------------------------------------------------------
extern "C" void kernel_launch(void* const* d_in, const int* in_sizes, int n_in,
                              void* d_out, int out_size, void* d_ws, size_t ws_size,
                              hipStream_t stream) {
  const float* fea    = (const float*)d_in[0];
  const float* w_qkv  = (const float*)d_in[1];
  const float* b_qkv  = (const float*)d_in[2];
  const float* w_out  = (const float*)d_in[3];
  const float* b_out  = (const float*)d_in[4];
  const float* conv_w = (const float*)d_in[5];
  float* out = (float*)d_out;

  __hip_bfloat16* xb    = (__hip_bfloat16*)d_ws;             // 4096*576
  __hip_bfloat16* WqkvT = xb + (size_t)L_TOK * D_DIM;        // 1728*576
  __hip_bfloat16* WoT   = WqkvT + (size_t)1728 * D_DIM;      // 576*576
  __hip_bfloat16* CwB   = WoT + (size_t)D_DIM * D_DIM;       // 128*576
  __hip_bfloat16* QKb   = CwB + (size_t)128 * D_DIM;         // 2*HSZ (Q,K)
  __hip_bfloat16* VbT   = QKb + 2 * HSZ;                     // HSZ (V^T)
  __hip_bfloat16* Opart = VbT + HSZ;                         // KSPLIT*8*4096*72
  float* Ml = (float*)(Opart + (size_t)KSPLIT * NHEADS * L_TOK * 72);
  // ob aliases QKb (Q,K dead after attn); xr aliases Opart (dead after merge)
  __hip_bfloat16* ob = QKb;
  __hip_bfloat16* xr = Opart;

  prep_all<<<1124, 256, 0, stream>>>(fea, w_qkv, w_out, conv_w, xb, WqkvT, WoT, CwB);
  gemm_mfma<0><<<dim3(32, 27), 256, 0, stream>>>(xb, WqkvT, b_qkv, nullptr, QKb, VbT);
  attn_mfma<<<512, 256, 0, stream>>>(QKb, QKb + HSZ, VbT, Opart, Ml);
  attn_merge<<<1152, 256, 0, stream>>>(Opart, Ml, ob);
  gemm_mfma<1><<<dim3(32, 9), 256, 0, stream>>>(ob, WoT, b_out, xb, xr, nullptr);
  final_small<<<dim3(128, 4), 256, 0, stream>>>(xr, CwB, out);
}